// Round 10
// baseline (279.549 us; speedup 1.0000x reference)
//
#include <hip/hip_runtime.h>
#include <math.h>

// ---------------------------------------------------------------------------
// DeepONet/GAT, fused pipeline (R10):
//   memset: BCUR (tiny)
//   preb  : feat1 logits only (es1/ed1, pre-scaled log2e) + W2->bf16^T
//           + POOLED zero + bin (edge bucket-sort into fixed arenas)
//   csr   : per-bucket CSR build (compact, window-local scatter)
//   a1f2  : LOW-RANK GAT1 agg: edge-parallel Σ w_e·x[src] (6 scalars/node,
//           LDS atomics) -> h1 = W1^T·sacc (reconstruct) -> MFMA -> xl2+logits2
//   a2pl  : GAT2 agg (shared weights) -> per-graph pools
//   tail  : counts + branch MLPs + combine + final head
// Buckets: 512 nodes (BSH=9), NB <= 128 (N <= 65536), arena 12288 edges.
// ---------------------------------------------------------------------------

#define BSH 9
#define CHUNK 4096
#define ARENA 12288
#define LOG2E 1.44269504088896f

using short8v = __attribute__((ext_vector_type(8))) short;
using f32x4  = __attribute__((ext_vector_type(4))) float;

__device__ __forceinline__ float leaky02(float x){ return fmaxf(x, 0.2f * x); }
__device__ __forceinline__ float elu1(float x){ return x > 0.f ? x : expm1f(x); }
__device__ __forceinline__ unsigned f2bf(float a){
    unsigned u = __float_as_uint(a);
    return (u + 0x7FFFu + ((u >> 16) & 1u)) >> 16;
}
__device__ __forceinline__ unsigned packbf(float a, float b){ return f2bf(a) | (f2bf(b) << 16); }
__device__ __forceinline__ float bflo(unsigned p){ return __uint_as_float(p << 16); }
__device__ __forceinline__ float bfhi(unsigned p){ return __uint_as_float(p & 0xFFFF0000u); }
__device__ __forceinline__ float bfs(unsigned short s){ return __uint_as_float(((unsigned)s) << 16); }

__device__ __forceinline__ int wave_incl_scan(int v, int lane){
    #pragma unroll
    for (int d = 1; d < 64; d <<= 1){ int u = __shfl_up(v, (unsigned)d, 64); if (lane >= d) v += u; }
    return v;
}

// feat1 logits + W2 transpose + POOLED zero + edge binning, grid-split.
__global__ __launch_bounds__(256) void preb_kernel(
    const float* __restrict__ xb, const float* __restrict__ xt,
    const float* __restrict__ W1b, const float* __restrict__ W1t,
    const float* __restrict__ a1sb, const float* __restrict__ a1st,
    const float* __restrict__ a1db, const float* __restrict__ a1dt,
    const int* __restrict__ eib, const int* __restrict__ eit,
    const float* __restrict__ W2b, const float* __restrict__ W2t,
    float* __restrict__ es1, float* __restrict__ ed1,
    int* __restrict__ bcur, unsigned* __restrict__ epair,
    unsigned short* __restrict__ w2T, float* __restrict__ pooled,
    int N, int E, int NB, int nodeBlocks, int histBlocks){
    int bid = blockIdx.x;
    int tid = threadIdx.x;
    __shared__ int hist[128], gpos[128];
    __shared__ int slots[CHUNK];
    if (bid < 2 * histBlocks){
        // ---- bin: bucket-sort one 4096-edge chunk into fixed arenas ----
        int br = (bid >= histBlocks) ? 1 : 0;
        int cb = bid - br * histBlocks;
        const int* ei = br ? eit : eib;
        int start = cb * CHUNK;
        int cnt = min(CHUNK, E - start);
        for (int i = tid; i < 128; i += 256) hist[i] = 0;
        __syncthreads();
        const int* dstp = ei + E + start;
        const int* srcp = ei + start;
        for (int li = tid; li < cnt; li += 256){
            int b = dstp[li] >> BSH;
            slots[li] = atomicAdd(&hist[b], 1);
        }
        __syncthreads();
        if (tid < NB){
            int h0 = hist[tid];
            gpos[tid] = (h0 > 0) ? atomicAdd(&bcur[br * NB + tid], h0) : 0;
        }
        __syncthreads();
        unsigned* ep = epair + (size_t)br * NB * ARENA;
        for (int li = tid; li < cnt; li += 256){
            int d = dstp[li];
            int b = d >> BSH;
            ep[(size_t)b * ARENA + gpos[b] + slots[li]] =
                ((unsigned)srcp[li] << BSH) | (unsigned)(d & ((1 << BSH) - 1));
        }
        return;
    }
    bid -= 2 * histBlocks;
    if (bid >= 2 * nodeBlocks){
        int xb2 = bid - 2 * nodeBlocks;
        if (xb2 < 2){
            // W2T[c][k] = bf16(W2[k][c]), per branch
            const float* W2 = xb2 ? W2t : W2b;
            for (int i = tid; i < 8192; i += 256){
                int c = i >> 7, k = i & 127;
                w2T[xb2 * 8192 + i] = (unsigned short)f2bf(W2[k * 64 + c]);
            }
        } else {
            for (int i = tid; i < 8192; i += 256) pooled[i] = 0.f;
        }
        return;
    }
    // ---- feat1 logits ----
    int br = (bid >= nodeBlocks) ? 1 : 0;
    int nb = bid - br * nodeBlocks;
    int n = (nb << 2) + (tid >> 6);
    int lane = tid & 63;
    if (n >= N) return;
    const float* x   = br ? xt   : xb;
    const float* W1  = br ? W1t  : W1b;
    const float* a1s = br ? a1st : a1sb;
    const float* a1d = br ? a1dt : a1db;
    float2 xv = ((const float2*)x)[n];
    float2 w0 = ((const float2*)W1)[lane];
    float2 w1 = ((const float2*)(W1 + 128))[lane];
    float xla = xv.x * w0.x + xv.y * w1.x;
    float xlb = xv.x * w0.y + xv.y * w1.y;
    float2 as = ((const float2*)a1s)[lane];
    float2 ad = ((const float2*)a1d)[lane];
    float ps = xla * as.x + xlb * as.y;
    float pd = xla * ad.x + xlb * ad.y;
    #pragma unroll
    for (int m = 16; m >= 1; m >>= 1){ ps += __shfl_xor(ps, m, 64); pd += __shfl_xor(pd, m, 64); }
    if ((lane & 31) == 0){
        int h = lane >> 5;
        es1[(size_t)br * N * 2 + n * 2 + h] = LOG2E * ps;
        ed1[(size_t)br * N * 2 + n * 2 + h] = LOG2E * pd;
    }
}

// per-bucket CSR: compact bases from bcur scan, local degrees, scatter src.
__global__ __launch_bounds__(256) void csr_kernel(
    const int* __restrict__ bcur, const unsigned* __restrict__ epair,
    int* __restrict__ rs, int* __restrict__ csr, int N, int E, int NB){
    int bid = blockIdx.x;
    int br = (bid >= NB) ? 1 : 0;
    int b = bid - br * NB;
    __shared__ int base2[128];
    __shared__ int deg[512], st[512];
    int tid = threadIdx.x, lane = tid & 63, wid = tid >> 6;
    if (wid == 0){
        int b0 = (lane < NB) ? bcur[br * NB + lane] : 0;
        int b1 = (64 + lane < NB) ? bcur[br * NB + 64 + lane] : 0;
        int g0 = wave_incl_scan(b0, lane); int gt = __shfl(g0, 63, 64);
        int g1 = wave_incl_scan(b1, lane);
        base2[lane] = g0 - b0; base2[64 + lane] = gt + g1 - b1;
    }
    for (int i = tid; i < 512; i += 256) deg[i] = 0;
    __syncthreads();
    int ebase = base2[b];
    int ecnt = bcur[br * NB + b];
    int n0 = b << BSH;
    int nodes = min(512, N - n0);
    const unsigned* ep = epair + ((size_t)br * NB + b) * ARENA;
    for (int i = tid; i < ecnt; i += 256) atomicAdd(&deg[ep[i] & 511u], 1);
    __syncthreads();
    if (wid == 0){
        int carry = 0;
        #pragma unroll
        for (int c = 0; c < 8; ++c){
            int v = deg[c * 64 + lane];
            int s = wave_incl_scan(v, lane);
            st[c * 64 + lane] = carry + s - v;
            carry += __shfl(s, 63, 64);
        }
    }
    __syncthreads();
    int* rsb = rs + (size_t)br * (N + 1);
    for (int i = tid; i < nodes; i += 256) rsb[n0 + i] = ebase + st[i];
    if (b == NB - 1 && tid == 0) rsb[N] = ebase + ecnt;
    for (int i = tid; i < 512; i += 256) deg[i] = st[i];
    __syncthreads();
    int* csrb = csr + (size_t)br * E + ebase;
    for (int i = tid; i < ecnt; i += 256){
        unsigned p = ep[i];
        int pos = atomicAdd(&deg[p & 511u], 1);
        csrb[pos] = (int)(p >> BSH);
    }
}

// Low-rank GAT1 aggregation + h1 reconstruction + (h1 @ W2T) MFMA + logits2.
// Block = 16 nodes, 256 threads:
//  A: stage rs window + dst logits in LDS
//  B: edge-parallel Sigma w_e*x[src] into sacc[16][6] (LDS f32 atomics)
//  C: self term
//  D: h1[row][c] = elu(W1^T sacc / denom + b1) -> hl (packed bf16, padded)
//  E: MFMA h1 @ W2T -> xl2 bf16 + es2/ed2
__global__ __launch_bounds__(256) void a1f2_kernel(
    const float* __restrict__ xB, const float* __restrict__ xT,
    const float* __restrict__ es1, const float* __restrict__ ed1,
    const int* __restrict__ csr, const int* __restrict__ rs,
    const float* __restrict__ W1b, const float* __restrict__ W1t,
    const float* __restrict__ b1b, const float* __restrict__ b1t,
    const unsigned short* __restrict__ w2T,
    const float* __restrict__ a2sb, const float* __restrict__ a2st,
    const float* __restrict__ a2db, const float* __restrict__ a2dt,
    unsigned short* __restrict__ xl2h, float* __restrict__ es2, float* __restrict__ ed2,
    int N, int E){
    int bid = blockIdx.x;
    int br = bid & 1;                 // branch parity == XCD parity class
    int n0 = (bid >> 1) << 4;
    const float* x  = br ? xT : xB;
    const float* es = es1 + (size_t)br * N * 2;
    const float* ed = ed1 + (size_t)br * N * 2;
    const int* cs = csr + (size_t)br * E;
    const int* rsb = rs + (size_t)br * (N + 1);
    const float* W1 = br ? W1t : W1b;
    const float* b1 = br ? b1t : b1b;
    const float* a2s = br ? a2st : a2sb;
    const float* a2d = br ? a2dt : a2db;

    __shared__ int rsl[17];
    __shared__ float edl[16][2];
    __shared__ float sacc[16][6];     // per node: d0, s0x, s0y, d1, s1x, s1y
    __shared__ unsigned hl[16][68];   // h1 tile, packed bf16 pairs, padded
    __shared__ float psa[4][16], pda[4][16];
    int tid = threadIdx.x, lane = tid & 63, w = tid >> 6;

    if (tid < 17) rsl[tid] = rsb[min(n0 + tid, N)];
    if (tid < 16){
        int nn = min(n0 + tid, N - 1);
        float2 edv = ((const float2*)ed)[nn];
        edl[tid][0] = edv.x; edl[tid][1] = edv.y;
    }
    if (tid < 96) ((float*)sacc)[tid] = 0.f;
    __syncthreads();

    // B: edge-parallel accumulation
    int ebeg = rsl[0], eend = rsl[16];
    for (int i = ebeg + tid; i < eend; i += 256){
        int s = cs[i];
        int lo = 0, hi = 16;
        while (hi - lo > 1){ int mid = (lo + hi) >> 1; if (rsl[mid] <= i) lo = mid; else hi = mid; }
        float2 xv = ((const float2*)x)[s];
        float2 ev = ((const float2*)es)[s];
        float w0 = exp2f(leaky02(ev.x + edl[lo][0]));
        float w1 = exp2f(leaky02(ev.y + edl[lo][1]));
        atomicAdd(&sacc[lo][0], w0);
        atomicAdd(&sacc[lo][1], w0 * xv.x);
        atomicAdd(&sacc[lo][2], w0 * xv.y);
        atomicAdd(&sacc[lo][3], w1);
        atomicAdd(&sacc[lo][4], w1 * xv.x);
        atomicAdd(&sacc[lo][5], w1 * xv.y);
    }
    __syncthreads();

    // C: self term
    if (tid < 16){
        int n = n0 + tid;
        if (n < N){
            float2 xv = ((const float2*)x)[n];
            float2 ev = ((const float2*)es)[n];
            float w0 = exp2f(leaky02(ev.x + edl[tid][0]));
            float w1 = exp2f(leaky02(ev.y + edl[tid][1]));
            sacc[tid][0] += w0; sacc[tid][1] += w0 * xv.x; sacc[tid][2] += w0 * xv.y;
            sacc[tid][3] += w1; sacc[tid][4] += w1 * xv.x; sacc[tid][5] += w1 * xv.y;
        }
    }
    __syncthreads();

    // D: reconstruct h1 = elu(W1^T sacc / denom + b1), packed 2ch/lane
    int h = lane >> 5;
    float2 w0c = ((const float2*)W1)[lane];          // W1[0, 2l..2l+1]
    float2 w1c = ((const float2*)(W1 + 128))[lane];  // W1[1, 2l..2l+1]
    float b1lo = b1[lane * 2], b1hi = b1[lane * 2 + 1];
    #pragma unroll
    for (int nn = 0; nn < 4; ++nn){
        int row = w * 4 + nn;
        int n = n0 + row;
        float dinv = 1.f / sacc[row][3 * h];
        float sx = sacc[row][3 * h + 1], sy = sacc[row][3 * h + 2];
        float va = (sx * w0c.x + sy * w1c.x) * dinv + b1lo;
        float vb = (sx * w0c.y + sy * w1c.y) * dinv + b1hi;
        hl[row][lane] = (n < N) ? packbf(elu1(va), elu1(vb)) : 0u;
    }

    int lr = lane & 15, lq = lane >> 4;
    // B fragments straight from global bf16 W2T (L1-resident 16KB/branch)
    const unsigned short* wtp = w2T + br * 8192 + (w * 16 + lr) * 128 + lq * 8;
    short8v bf0 = *(const short8v*)(wtp);
    short8v bf1 = *(const short8v*)(wtp + 32);
    short8v bf2 = *(const short8v*)(wtp + 64);
    short8v bf3 = *(const short8v*)(wtp + 96);
    __syncthreads();
    f32x4 ac = {0.f, 0.f, 0.f, 0.f};
    ac = __builtin_amdgcn_mfma_f32_16x16x32_bf16(*(const short8v*)&hl[lr][lq * 4], bf0, ac, 0, 0, 0);
    ac = __builtin_amdgcn_mfma_f32_16x16x32_bf16(*(const short8v*)&hl[lr][16 + lq * 4], bf1, ac, 0, 0, 0);
    ac = __builtin_amdgcn_mfma_f32_16x16x32_bf16(*(const short8v*)&hl[lr][32 + lq * 4], bf2, ac, 0, 0, 0);
    ac = __builtin_amdgcn_mfma_f32_16x16x32_bf16(*(const short8v*)&hl[lr][48 + lq * 4], bf3, ac, 0, 0, 0);
    float a2sv = a2s[w * 16 + lr];
    float a2dv = a2d[w * 16 + lr];
    #pragma unroll
    for (int reg = 0; reg < 4; ++reg){
        int r = lq * 4 + reg;
        int n = n0 + r;
        float v = ac[reg];
        if (n < N)
            xl2h[((size_t)br * N + n) * 64 + w * 16 + lr] = (unsigned short)f2bf(v);
        float ps = v * a2sv, pd = v * a2dv;
        ps += __shfl_xor(ps, 1, 64); ps += __shfl_xor(ps, 2, 64);
        ps += __shfl_xor(ps, 4, 64); ps += __shfl_xor(ps, 8, 64);
        pd += __shfl_xor(pd, 1, 64); pd += __shfl_xor(pd, 2, 64);
        pd += __shfl_xor(pd, 4, 64); pd += __shfl_xor(pd, 8, 64);
        if (lr == 0){ psa[w][r] = ps; pda[w][r] = pd; }
    }
    __syncthreads();
    if (tid < 16){
        int n = n0 + tid;
        if (n < N)
            es2[(size_t)br * N + n] = LOG2E * (psa[0][tid] + psa[1][tid] + psa[2][tid] + psa[3][tid]);
    } else if (tid < 32){
        int r = tid - 16;
        int n = n0 + r;
        if (n < N)
            ed2[(size_t)br * N + n] = LOG2E * (pda[0][r] + pda[1][r] + pda[2][r] + pda[3][r]);
    }
}

// Fused GAT2 aggregation + per-graph pooled sums. Full-row ushort gathers,
// shared edge-weight computation, scalar indices, 32-bit addressing.
__global__ __launch_bounds__(256) void a2pl_kernel(
    const unsigned short* __restrict__ xl2h, const float* __restrict__ es2, const float* __restrict__ ed2,
    const int* __restrict__ csr, const int* __restrict__ rs,
    const float* __restrict__ b2b, const float* __restrict__ b2t,
    const int* __restrict__ batchb, const int* __restrict__ batcht,
    float* __restrict__ pooled, int N, int E){
    int bid = blockIdx.x;
    int br = bid & 1;                 // branch parity == XCD parity class
    int tid = threadIdx.x, lane = tid & 63, w = tid >> 6;
    int n = ((bid >> 1) << 2) + w;
    const unsigned short* xlt = xl2h + (size_t)br * N * 64;
    const float* es = es2 + (size_t)br * N;
    const float* ed = ed2 + (size_t)br * N;
    const int* cs = csr + (size_t)br * E;
    const int* rsb = rs + (size_t)br * (N + 1);
    const float* b2 = br ? b2t : b2b;
    const int* batch = br ? batcht : batchb;
    float hv = 0.f;
    int g = -1;
    if (n < N){
        float edn = ed[n];
        float wself = exp2f(leaky02(es[n] + edn));
        float denom = wself;
        float acc = wself * bfs(xlt[(unsigned)(n * 64) + lane]);
        int beg = __builtin_amdgcn_readfirstlane(rsb[n]);
        int end = __builtin_amdgcn_readfirstlane(rsb[n + 1]);
        int j = beg;
        for (; j + 8 <= end; j += 8){
            int svec = cs[j + (lane & 7)];
            float ev = es[svec];
            float wmine = exp2f(leaky02(ev + edn));
            int ss[8]; float vv[8], wq[8];
            #pragma unroll
            for (int q = 0; q < 8; ++q) ss[q] = __builtin_amdgcn_readfirstlane(cs[j + q]);
            #pragma unroll
            for (int q = 0; q < 8; ++q) vv[q] = bfs(xlt[(unsigned)(ss[q] * 64) + lane]);
            #pragma unroll
            for (int q = 0; q < 8; ++q) wq[q] = __shfl(wmine, q, 64);
            #pragma unroll
            for (int q = 0; q < 8; ++q){
                denom += wq[q];
                acc += wq[q] * vv[q];
            }
        }
        for (; j < end; ++j){
            int s = __builtin_amdgcn_readfirstlane(cs[j]);
            float wqv = exp2f(leaky02(es[s] + edn));
            denom += wqv;
            acc += wqv * bfs(xlt[(unsigned)(s * 64) + lane]);
        }
        hv = elu1(acc / denom + b2[lane]);
        g = batch[n];
    }
    __shared__ float red[4][64];
    __shared__ int gid[4];
    red[w][lane] = hv;
    if (lane == 0) gid[w] = g;
    __syncthreads();
    if (w == 0){
        int g0 = gid[0], g1 = gid[1], g2 = gid[2], g3 = gid[3];
        float* pb = pooled + (size_t)br * 4096;
        if (g0 >= 0 && g0 == g1 && g1 == g2 && g2 == g3){
            float s = (red[0][lane] + red[1][lane]) + (red[2][lane] + red[3][lane]);
            atomicAdd(&pb[g0 * 64 + lane], s);
        } else {
            #pragma unroll
            for (int q = 0; q < 4; ++q)
                if (gid[q] >= 0) atomicAdd(&pb[gid[q] * 64 + lane], red[q][lane]);
        }
    }
}

// counts (binary search on sorted batch) + branch MLPs + combine + final head
__global__ __launch_bounds__(1024) void tail_kernel(
    const float* __restrict__ pooled,
    const int* __restrict__ batchb, const int* __restrict__ batcht,
    const float* __restrict__ M1wb, const float* __restrict__ M1bb,
    const float* __restrict__ M2wb, const float* __restrict__ M2bb,
    const float* __restrict__ M1wt, const float* __restrict__ M1bt,
    const float* __restrict__ M2wt, const float* __restrict__ M2bt,
    const float* __restrict__ Fw1, const float* __restrict__ Fb1,
    const float* __restrict__ Fw2, const float* __restrict__ Fb2,
    float* __restrict__ out, int N){
    __shared__ float P[8192];
    __shared__ float H[8192];
    __shared__ float cl[128];
    int t = threadIdx.x;
    if (t < 128){
        int br = t >> 6, g = t & 63;
        const int* batch = br ? batcht : batchb;
        int lo = 0, hi = N;
        while (lo < hi){ int mid = (lo + hi) >> 1; if (batch[mid] < g) lo = mid + 1; else hi = mid; }
        int beg = lo;
        hi = N;
        while (lo < hi){ int mid = (lo + hi) >> 1; if (batch[mid] < g + 1) lo = mid + 1; else hi = mid; }
        cl[t] = (float)(lo - beg);
    }
    __syncthreads();
    for (int i = t; i < 8192; i += 1024)
        P[i] = pooled[i] / fmaxf(cl[i >> 6], 1.f);
    __syncthreads();
    for (int i = t; i < 8192; i += 1024){
        int br = i >> 12, r = (i >> 6) & 63, c = i & 63;
        const float* M1w = br ? M1wt : M1wb;
        const float* M1b = br ? M1bt : M1bb;
        float acc = M1b[c];
        int pb = (br << 12) + (r << 6);
        #pragma unroll 8
        for (int k = 0; k < 64; ++k) acc += P[pb + k] * M1w[(k << 6) + c];
        H[i] = fmaxf(acc, 0.f);
    }
    __syncthreads();
    for (int i = t; i < 8192; i += 1024){
        int br = i >> 12, r = (i >> 6) & 63, c = i & 63;
        const float* M2w = br ? M2wt : M2wb;
        const float* M2b = br ? M2bt : M2bb;
        float acc = M2b[c];
        int hb = (br << 12) + (r << 6);
        #pragma unroll 8
        for (int k = 0; k < 64; ++k) acc += H[hb + k] * M2w[(k << 6) + c];
        P[i] = acc;
    }
    __syncthreads();
    for (int i = t; i < 4096; i += 1024) H[i] = P[i] * P[4096 + i];
    __syncthreads();
    for (int i = t; i < 4096; i += 1024){
        int r = i >> 6, c = i & 63;
        float acc = Fb1[c];
        #pragma unroll 8
        for (int k = 0; k < 64; ++k) acc += H[(r << 6) + k] * Fw1[(k << 6) + c];
        P[i] = fmaxf(acc, 0.f);
    }
    __syncthreads();
    if (t < 128){
        int r = t >> 1, jc = t & 1;
        float acc = Fb2[jc];
        #pragma unroll 8
        for (int k = 0; k < 64; ++k) acc += P[(r << 6) + k] * Fw2[k * 2 + jc];
        out[t] = tanhf(acc);
    }
}

extern "C" void kernel_launch(void* const* d_in, const int* in_sizes, int n_in,
                              void* d_out, int out_size, void* d_ws, size_t ws_size,
                              hipStream_t stream){
    const int N = in_sizes[0] / 2;
    const int E = in_sizes[1] / 2;
    const int NB = (N + 511) >> BSH;   // nodes-per-bucket = 512, NB <= 128

    char* ws = (char*)d_ws;
    size_t off = 0;
    auto alloc = [&](size_t bytes) -> char* {
        char* p = ws + off;
        off += (bytes + 255) & ~(size_t)255;
        return p;
    };
    unsigned short* XL2h = (unsigned short*)alloc((size_t)2 * N * 64 * 2);  // EPAIR aliases this
    float* ES1 = (float*)alloc((size_t)2 * N * 2 * 4);
    float* ED1 = (float*)alloc((size_t)2 * N * 2 * 4);
    float* ES2 = (float*)alloc((size_t)2 * N * 4);
    float* ED2 = (float*)alloc((size_t)2 * N * 4);
    int* RS  = (int*)alloc((size_t)2 * (N + 1) * 4);
    int* CSR = (int*)alloc((size_t)2 * E * 4);
    int* BCUR = (int*)alloc((size_t)2 * NB * 4);
    float* POOLED = (float*)alloc(8192 * 4);
    unsigned short* W2T = (unsigned short*)alloc(2 * 8192 * 2);
    unsigned* EPAIR = (unsigned*)XL2h;   // 2*NB*ARENA*4 <= 2*N*128 bytes; dead after csr

    const float* xb   = (const float*)d_in[0];
    const int*   eib  = (const int*)  d_in[1];
    const int*   batchb = (const int*)d_in[2];
    const float* W1b  = (const float*)d_in[3];
    const float* a1sb = (const float*)d_in[4];
    const float* a1db = (const float*)d_in[5];
    const float* b1b  = (const float*)d_in[6];
    const float* W2b  = (const float*)d_in[7];
    const float* a2sb = (const float*)d_in[8];
    const float* a2db = (const float*)d_in[9];
    const float* b2b  = (const float*)d_in[10];
    const float* M1wb = (const float*)d_in[11];
    const float* M1bb = (const float*)d_in[12];
    const float* M2wb = (const float*)d_in[13];
    const float* M2bb = (const float*)d_in[14];
    const float* xt   = (const float*)d_in[15];
    const int*   eit  = (const int*)  d_in[16];
    const int*   batcht = (const int*)d_in[17];
    const float* W1t  = (const float*)d_in[18];
    const float* a1st = (const float*)d_in[19];
    const float* a1dt = (const float*)d_in[20];
    const float* b1t  = (const float*)d_in[21];
    const float* W2t  = (const float*)d_in[22];
    const float* a2st = (const float*)d_in[23];
    const float* a2dt = (const float*)d_in[24];
    const float* b2t  = (const float*)d_in[25];
    const float* M1wt = (const float*)d_in[26];
    const float* M1bt = (const float*)d_in[27];
    const float* M2wt = (const float*)d_in[28];
    const float* M2bt = (const float*)d_in[29];
    const float* Fw1  = (const float*)d_in[30];
    const float* Fb1  = (const float*)d_in[31];
    const float* Fw2  = (const float*)d_in[32];
    const float* Fb2  = (const float*)d_in[33];

    const int nodeBlocks = (N + 3) / 4;
    const int histBlocks = (E + CHUNK - 1) / CHUNK;
    const int tilesPer   = (N + 15) / 16;

    hipMemsetAsync(BCUR, 0, (size_t)2 * NB * 4, stream);
    preb_kernel<<<2 * histBlocks + 2 * nodeBlocks + 3, 256, 0, stream>>>(
        xb, xt, W1b, W1t, a1sb, a1st, a1db, a1dt, eib, eit, W2b, W2t,
        ES1, ED1, BCUR, EPAIR, W2T, POOLED, N, E, NB, nodeBlocks, histBlocks);
    csr_kernel<<<2 * NB, 256, 0, stream>>>(BCUR, EPAIR, RS, CSR, N, E, NB);
    a1f2_kernel<<<2 * tilesPer, 256, 0, stream>>>(
        xb, xt, ES1, ED1, CSR, RS, W1b, W1t, b1b, b1t, W2T,
        a2sb, a2st, a2db, a2dt, XL2h, ES2, ED2, N, E);
    a2pl_kernel<<<2 * nodeBlocks, 256, 0, stream>>>(
        XL2h, ES2, ED2, CSR, RS, b2b, b2t, batchb, batcht, POOLED, N, E);
    tail_kernel<<<1, 1024, 0, stream>>>(POOLED, batchb, batcht,
        M1wb, M1bb, M2wb, M2bb, M1wt, M1bt, M2wt, M2bt,
        Fw1, Fb1, Fw2, Fb2, (float*)d_out, N);
}

// Round 11
// 225.185 us; speedup vs baseline: 1.2414x; 1.2414x over previous
//
#include <hip/hip_runtime.h>
#include <math.h>

// ---------------------------------------------------------------------------
// DeepONet/GAT, fused pipeline (R11):
//   memset: BCUR (tiny)
//   preb  : feat1 logits only (es1/ed1, pre-scaled log2e) + W2->bf16^T
//           + POOLED zero + bin (edge bucket-sort into fixed arenas)
//   csr   : per-bucket CSR build (compact, window-local scatter)
//   a1f2  : LOW-RANK GAT1 agg, 8 lanes/node (shfl-tree reduce, no LDS atomics,
//           no binary search) -> h1 = W1^T·sacc -> MFMA (32-row tile) -> xl2
//   a2pl  : GAT2 agg (shared weights) -> per-graph pools
//   tail  : counts + branch MLPs + combine + final head
// Buckets: 512 nodes (BSH=9), NB <= 128 (N <= 65536), arena 12288 edges.
// ---------------------------------------------------------------------------

#define BSH 9
#define CHUNK 4096
#define ARENA 12288
#define LOG2E 1.44269504088896f

using short8v = __attribute__((ext_vector_type(8))) short;
using f32x4  = __attribute__((ext_vector_type(4))) float;

__device__ __forceinline__ float leaky02(float x){ return fmaxf(x, 0.2f * x); }
__device__ __forceinline__ float elu1(float x){ return x > 0.f ? x : expm1f(x); }
__device__ __forceinline__ unsigned f2bf(float a){
    unsigned u = __float_as_uint(a);
    return (u + 0x7FFFu + ((u >> 16) & 1u)) >> 16;
}
__device__ __forceinline__ unsigned packbf(float a, float b){ return f2bf(a) | (f2bf(b) << 16); }
__device__ __forceinline__ float bflo(unsigned p){ return __uint_as_float(p << 16); }
__device__ __forceinline__ float bfhi(unsigned p){ return __uint_as_float(p & 0xFFFF0000u); }
__device__ __forceinline__ float bfs(unsigned short s){ return __uint_as_float(((unsigned)s) << 16); }

__device__ __forceinline__ int wave_incl_scan(int v, int lane){
    #pragma unroll
    for (int d = 1; d < 64; d <<= 1){ int u = __shfl_up(v, (unsigned)d, 64); if (lane >= d) v += u; }
    return v;
}

// feat1 logits + W2 transpose + POOLED zero + edge binning, grid-split.
__global__ __launch_bounds__(256) void preb_kernel(
    const float* __restrict__ xb, const float* __restrict__ xt,
    const float* __restrict__ W1b, const float* __restrict__ W1t,
    const float* __restrict__ a1sb, const float* __restrict__ a1st,
    const float* __restrict__ a1db, const float* __restrict__ a1dt,
    const int* __restrict__ eib, const int* __restrict__ eit,
    const float* __restrict__ W2b, const float* __restrict__ W2t,
    float* __restrict__ es1, float* __restrict__ ed1,
    int* __restrict__ bcur, unsigned* __restrict__ epair,
    unsigned short* __restrict__ w2T, float* __restrict__ pooled,
    int N, int E, int NB, int nodeBlocks, int histBlocks){
    int bid = blockIdx.x;
    int tid = threadIdx.x;
    __shared__ int hist[128], gpos[128];
    __shared__ int slots[CHUNK];
    if (bid < 2 * histBlocks){
        // ---- bin: bucket-sort one 4096-edge chunk into fixed arenas ----
        int br = (bid >= histBlocks) ? 1 : 0;
        int cb = bid - br * histBlocks;
        const int* ei = br ? eit : eib;
        int start = cb * CHUNK;
        int cnt = min(CHUNK, E - start);
        for (int i = tid; i < 128; i += 256) hist[i] = 0;
        __syncthreads();
        const int* dstp = ei + E + start;
        const int* srcp = ei + start;
        for (int li = tid; li < cnt; li += 256){
            int b = dstp[li] >> BSH;
            slots[li] = atomicAdd(&hist[b], 1);
        }
        __syncthreads();
        if (tid < NB){
            int h0 = hist[tid];
            gpos[tid] = (h0 > 0) ? atomicAdd(&bcur[br * NB + tid], h0) : 0;
        }
        __syncthreads();
        unsigned* ep = epair + (size_t)br * NB * ARENA;
        for (int li = tid; li < cnt; li += 256){
            int d = dstp[li];
            int b = d >> BSH;
            ep[(size_t)b * ARENA + gpos[b] + slots[li]] =
                ((unsigned)srcp[li] << BSH) | (unsigned)(d & ((1 << BSH) - 1));
        }
        return;
    }
    bid -= 2 * histBlocks;
    if (bid >= 2 * nodeBlocks){
        int xb2 = bid - 2 * nodeBlocks;
        if (xb2 < 2){
            // W2T[c][k] = bf16(W2[k][c]), per branch
            const float* W2 = xb2 ? W2t : W2b;
            for (int i = tid; i < 8192; i += 256){
                int c = i >> 7, k = i & 127;
                w2T[xb2 * 8192 + i] = (unsigned short)f2bf(W2[k * 64 + c]);
            }
        } else {
            for (int i = tid; i < 8192; i += 256) pooled[i] = 0.f;
        }
        return;
    }
    // ---- feat1 logits ----
    int br = (bid >= nodeBlocks) ? 1 : 0;
    int nb = bid - br * nodeBlocks;
    int n = (nb << 2) + (tid >> 6);
    int lane = tid & 63;
    if (n >= N) return;
    const float* x   = br ? xt   : xb;
    const float* W1  = br ? W1t  : W1b;
    const float* a1s = br ? a1st : a1sb;
    const float* a1d = br ? a1dt : a1db;
    float2 xv = ((const float2*)x)[n];
    float2 w0 = ((const float2*)W1)[lane];
    float2 w1 = ((const float2*)(W1 + 128))[lane];
    float xla = xv.x * w0.x + xv.y * w1.x;
    float xlb = xv.x * w0.y + xv.y * w1.y;
    float2 as = ((const float2*)a1s)[lane];
    float2 ad = ((const float2*)a1d)[lane];
    float ps = xla * as.x + xlb * as.y;
    float pd = xla * ad.x + xlb * ad.y;
    #pragma unroll
    for (int m = 16; m >= 1; m >>= 1){ ps += __shfl_xor(ps, m, 64); pd += __shfl_xor(pd, m, 64); }
    if ((lane & 31) == 0){
        int h = lane >> 5;
        es1[(size_t)br * N * 2 + n * 2 + h] = LOG2E * ps;
        ed1[(size_t)br * N * 2 + n * 2 + h] = LOG2E * pd;
    }
}

// per-bucket CSR: compact bases from bcur scan, local degrees, scatter src.
__global__ __launch_bounds__(256) void csr_kernel(
    const int* __restrict__ bcur, const unsigned* __restrict__ epair,
    int* __restrict__ rs, int* __restrict__ csr, int N, int E, int NB){
    int bid = blockIdx.x;
    int br = (bid >= NB) ? 1 : 0;
    int b = bid - br * NB;
    __shared__ int base2[128];
    __shared__ int deg[512], st[512];
    int tid = threadIdx.x, lane = tid & 63, wid = tid >> 6;
    if (wid == 0){
        int b0 = (lane < NB) ? bcur[br * NB + lane] : 0;
        int b1 = (64 + lane < NB) ? bcur[br * NB + 64 + lane] : 0;
        int g0 = wave_incl_scan(b0, lane); int gt = __shfl(g0, 63, 64);
        int g1 = wave_incl_scan(b1, lane);
        base2[lane] = g0 - b0; base2[64 + lane] = gt + g1 - b1;
    }
    for (int i = tid; i < 512; i += 256) deg[i] = 0;
    __syncthreads();
    int ebase = base2[b];
    int ecnt = bcur[br * NB + b];
    int n0 = b << BSH;
    int nodes = min(512, N - n0);
    const unsigned* ep = epair + ((size_t)br * NB + b) * ARENA;
    for (int i = tid; i < ecnt; i += 256) atomicAdd(&deg[ep[i] & 511u], 1);
    __syncthreads();
    if (wid == 0){
        int carry = 0;
        #pragma unroll
        for (int c = 0; c < 8; ++c){
            int v = deg[c * 64 + lane];
            int s = wave_incl_scan(v, lane);
            st[c * 64 + lane] = carry + s - v;
            carry += __shfl(s, 63, 64);
        }
    }
    __syncthreads();
    int* rsb = rs + (size_t)br * (N + 1);
    for (int i = tid; i < nodes; i += 256) rsb[n0 + i] = ebase + st[i];
    if (b == NB - 1 && tid == 0) rsb[N] = ebase + ecnt;
    for (int i = tid; i < 512; i += 256) deg[i] = st[i];
    __syncthreads();
    int* csrb = csr + (size_t)br * E + ebase;
    for (int i = tid; i < ecnt; i += 256){
        unsigned p = ep[i];
        int pos = atomicAdd(&deg[p & 511u], 1);
        csrb[pos] = (int)(p >> BSH);
    }
}

// Low-rank GAT1 aggregation (8 lanes/node) + h1 reconstruction + MFMA + logits2.
// Block = 32 nodes, 4 waves; wave = 8 nodes, 8 lanes each.
__global__ __launch_bounds__(256) void a1f2_kernel(
    const float* __restrict__ xB, const float* __restrict__ xT,
    const float* __restrict__ es1, const float* __restrict__ ed1,
    const int* __restrict__ csr, const int* __restrict__ rs,
    const float* __restrict__ W1b, const float* __restrict__ W1t,
    const float* __restrict__ b1b, const float* __restrict__ b1t,
    const unsigned short* __restrict__ w2T,
    const float* __restrict__ a2sb, const float* __restrict__ a2st,
    const float* __restrict__ a2db, const float* __restrict__ a2dt,
    unsigned short* __restrict__ xl2h, float* __restrict__ es2, float* __restrict__ ed2,
    int N, int E){
    int bid = blockIdx.x;
    int br = bid & 1;                 // branch parity == XCD parity class
    int n0 = (bid >> 1) << 5;         // 32 nodes per block
    const float* x  = br ? xT : xB;
    const float* es = es1 + (size_t)br * N * 2;
    const float* ed = ed1 + (size_t)br * N * 2;
    const int* cs = csr + (size_t)br * E;
    const int* rsb = rs + (size_t)br * (N + 1);
    const float* W1 = br ? W1t : W1b;
    const float* b1 = br ? b1t : b1b;
    const float* a2s = br ? a2st : a2sb;
    const float* a2d = br ? a2dt : a2db;

    __shared__ float sacc[32][6];     // per node: d0, s0x, s0y, d1, s1x, s1y
    __shared__ unsigned hl[32][68];   // h1 tile, packed bf16 pairs, padded
    __shared__ float psa[4][32], pda[4][32];
    int tid = threadIdx.x, lane = tid & 63, w = tid >> 6;
    int g = lane >> 3, sl = lane & 7;
    int row = w * 8 + g;
    int n = n0 + row;
    bool valid = n < N;

    // ---- aggregation: 8 lanes per node, register accumulators ----
    float2 edv = ((const float2*)ed)[valid ? n : 0];
    int beg = 0, end = 0;
    if (valid){ beg = rsb[n]; end = rsb[n + 1]; }
    float d0 = 0.f, s0x = 0.f, s0y = 0.f, d1 = 0.f, s1x = 0.f, s1y = 0.f;
    if (valid && sl == 0){            // self-loop term
        float2 xv = ((const float2*)x)[n];
        float2 ev = ((const float2*)es)[n];
        float w0 = exp2f(leaky02(ev.x + edv.x));
        float w1 = exp2f(leaky02(ev.y + edv.y));
        d0 = w0; s0x = w0 * xv.x; s0y = w0 * xv.y;
        d1 = w1; s1x = w1 * xv.x; s1y = w1 * xv.y;
    }
    for (int j = beg + sl; j < end; j += 8){
        int s = cs[j];
        float2 xv = ((const float2*)x)[s];
        float2 ev = ((const float2*)es)[s];
        float w0 = exp2f(leaky02(ev.x + edv.x));
        float w1 = exp2f(leaky02(ev.y + edv.y));
        d0 += w0; s0x += w0 * xv.x; s0y += w0 * xv.y;
        d1 += w1; s1x += w1 * xv.x; s1y += w1 * xv.y;
    }
    #pragma unroll
    for (int m = 1; m < 8; m <<= 1){
        d0  += __shfl_xor(d0, m, 64);
        s0x += __shfl_xor(s0x, m, 64);
        s0y += __shfl_xor(s0y, m, 64);
        d1  += __shfl_xor(d1, m, 64);
        s1x += __shfl_xor(s1x, m, 64);
        s1y += __shfl_xor(s1y, m, 64);
    }
    if (sl == 0){
        sacc[row][0] = d0; sacc[row][1] = s0x; sacc[row][2] = s0y;
        sacc[row][3] = d1; sacc[row][4] = s1x; sacc[row][5] = s1y;
    }
    __syncthreads();

    // ---- reconstruct h1 = elu(W1^T sacc / denom + b1), 8 rows per wave ----
    int h = lane >> 5;
    float2 w0c = ((const float2*)W1)[lane];          // W1[0, 2l..2l+1]
    float2 w1c = ((const float2*)(W1 + 128))[lane];  // W1[1, 2l..2l+1]
    float b1lo = b1[lane * 2], b1hi = b1[lane * 2 + 1];
    #pragma unroll
    for (int nn = 0; nn < 8; ++nn){
        int r2 = w * 8 + nn;
        int nr = n0 + r2;
        float dinv = 1.f / sacc[r2][3 * h];
        float sx = sacc[r2][3 * h + 1], sy = sacc[r2][3 * h + 2];
        float va = (sx * w0c.x + sy * w1c.x) * dinv + b1lo;
        float vb = (sx * w0c.y + sy * w1c.y) * dinv + b1hi;
        hl[r2][lane] = (nr < N) ? packbf(elu1(va), elu1(vb)) : 0u;
    }

    int lr = lane & 15, lq = lane >> 4;
    // B fragments straight from global bf16 W2T (L1-resident 16KB/branch)
    const unsigned short* wtp = w2T + br * 8192 + (w * 16 + lr) * 128 + lq * 8;
    short8v bf0 = *(const short8v*)(wtp);
    short8v bf1 = *(const short8v*)(wtp + 32);
    short8v bf2 = *(const short8v*)(wtp + 64);
    short8v bf3 = *(const short8v*)(wtp + 96);
    float a2sv = a2s[w * 16 + lr];
    float a2dv = a2d[w * 16 + lr];
    __syncthreads();
    // ---- MFMA: 2 row-tiles x this wave's 16-col tile ----
    #pragma unroll
    for (int rt = 0; rt < 2; ++rt){
        int rb = rt << 4;
        f32x4 ac = {0.f, 0.f, 0.f, 0.f};
        ac = __builtin_amdgcn_mfma_f32_16x16x32_bf16(*(const short8v*)&hl[rb + lr][lq * 4], bf0, ac, 0, 0, 0);
        ac = __builtin_amdgcn_mfma_f32_16x16x32_bf16(*(const short8v*)&hl[rb + lr][16 + lq * 4], bf1, ac, 0, 0, 0);
        ac = __builtin_amdgcn_mfma_f32_16x16x32_bf16(*(const short8v*)&hl[rb + lr][32 + lq * 4], bf2, ac, 0, 0, 0);
        ac = __builtin_amdgcn_mfma_f32_16x16x32_bf16(*(const short8v*)&hl[rb + lr][48 + lq * 4], bf3, ac, 0, 0, 0);
        #pragma unroll
        for (int reg = 0; reg < 4; ++reg){
            int r = rb + lq * 4 + reg;
            int nr = n0 + r;
            float v = ac[reg];
            if (nr < N)
                xl2h[((size_t)br * N + nr) * 64 + w * 16 + lr] = (unsigned short)f2bf(v);
            float ps = v * a2sv, pd = v * a2dv;
            ps += __shfl_xor(ps, 1, 64); ps += __shfl_xor(ps, 2, 64);
            ps += __shfl_xor(ps, 4, 64); ps += __shfl_xor(ps, 8, 64);
            pd += __shfl_xor(pd, 1, 64); pd += __shfl_xor(pd, 2, 64);
            pd += __shfl_xor(pd, 4, 64); pd += __shfl_xor(pd, 8, 64);
            if (lr == 0){ psa[w][r] = ps; pda[w][r] = pd; }
        }
    }
    __syncthreads();
    if (tid < 32){
        int nr = n0 + tid;
        if (nr < N)
            es2[(size_t)br * N + nr] = LOG2E * (psa[0][tid] + psa[1][tid] + psa[2][tid] + psa[3][tid]);
    } else if (tid < 64){
        int r = tid - 32;
        int nr = n0 + r;
        if (nr < N)
            ed2[(size_t)br * N + nr] = LOG2E * (pda[0][r] + pda[1][r] + pda[2][r] + pda[3][r]);
    }
}

// Fused GAT2 aggregation + per-graph pooled sums. Full-row ushort gathers,
// shared edge-weight computation, scalar indices, 32-bit addressing.
__global__ __launch_bounds__(256) void a2pl_kernel(
    const unsigned short* __restrict__ xl2h, const float* __restrict__ es2, const float* __restrict__ ed2,
    const int* __restrict__ csr, const int* __restrict__ rs,
    const float* __restrict__ b2b, const float* __restrict__ b2t,
    const int* __restrict__ batchb, const int* __restrict__ batcht,
    float* __restrict__ pooled, int N, int E){
    int bid = blockIdx.x;
    int br = bid & 1;                 // branch parity == XCD parity class
    int tid = threadIdx.x, lane = tid & 63, w = tid >> 6;
    int n = ((bid >> 1) << 2) + w;
    const unsigned short* xlt = xl2h + (size_t)br * N * 64;
    const float* es = es2 + (size_t)br * N;
    const float* ed = ed2 + (size_t)br * N;
    const int* cs = csr + (size_t)br * E;
    const int* rsb = rs + (size_t)br * (N + 1);
    const float* b2 = br ? b2t : b2b;
    const int* batch = br ? batcht : batchb;
    float hv = 0.f;
    int g = -1;
    if (n < N){
        float edn = ed[n];
        float wself = exp2f(leaky02(es[n] + edn));
        float denom = wself;
        float acc = wself * bfs(xlt[(unsigned)(n * 64) + lane]);
        int beg = __builtin_amdgcn_readfirstlane(rsb[n]);
        int end = __builtin_amdgcn_readfirstlane(rsb[n + 1]);
        int j = beg;
        for (; j + 8 <= end; j += 8){
            int svec = cs[j + (lane & 7)];
            float ev = es[svec];
            float wmine = exp2f(leaky02(ev + edn));
            int ss[8]; float vv[8], wq[8];
            #pragma unroll
            for (int q = 0; q < 8; ++q) ss[q] = __builtin_amdgcn_readfirstlane(cs[j + q]);
            #pragma unroll
            for (int q = 0; q < 8; ++q) vv[q] = bfs(xlt[(unsigned)(ss[q] * 64) + lane]);
            #pragma unroll
            for (int q = 0; q < 8; ++q) wq[q] = __shfl(wmine, q, 64);
            #pragma unroll
            for (int q = 0; q < 8; ++q){
                denom += wq[q];
                acc += wq[q] * vv[q];
            }
        }
        for (; j < end; ++j){
            int s = __builtin_amdgcn_readfirstlane(cs[j]);
            float wqv = exp2f(leaky02(es[s] + edn));
            denom += wqv;
            acc += wqv * bfs(xlt[(unsigned)(s * 64) + lane]);
        }
        hv = elu1(acc / denom + b2[lane]);
        g = batch[n];
    }
    __shared__ float red[4][64];
    __shared__ int gid[4];
    red[w][lane] = hv;
    if (lane == 0) gid[w] = g;
    __syncthreads();
    if (w == 0){
        int g0 = gid[0], g1 = gid[1], g2 = gid[2], g3 = gid[3];
        float* pb = pooled + (size_t)br * 4096;
        if (g0 >= 0 && g0 == g1 && g1 == g2 && g2 == g3){
            float s = (red[0][lane] + red[1][lane]) + (red[2][lane] + red[3][lane]);
            atomicAdd(&pb[g0 * 64 + lane], s);
        } else {
            #pragma unroll
            for (int q = 0; q < 4; ++q)
                if (gid[q] >= 0) atomicAdd(&pb[gid[q] * 64 + lane], red[q][lane]);
        }
    }
}

// counts (binary search on sorted batch) + branch MLPs + combine + final head
__global__ __launch_bounds__(1024) void tail_kernel(
    const float* __restrict__ pooled,
    const int* __restrict__ batchb, const int* __restrict__ batcht,
    const float* __restrict__ M1wb, const float* __restrict__ M1bb,
    const float* __restrict__ M2wb, const float* __restrict__ M2bb,
    const float* __restrict__ M1wt, const float* __restrict__ M1bt,
    const float* __restrict__ M2wt, const float* __restrict__ M2bt,
    const float* __restrict__ Fw1, const float* __restrict__ Fb1,
    const float* __restrict__ Fw2, const float* __restrict__ Fb2,
    float* __restrict__ out, int N){
    __shared__ float P[8192];
    __shared__ float H[8192];
    __shared__ float cl[128];
    int t = threadIdx.x;
    if (t < 128){
        int br = t >> 6, g = t & 63;
        const int* batch = br ? batcht : batchb;
        int lo = 0, hi = N;
        while (lo < hi){ int mid = (lo + hi) >> 1; if (batch[mid] < g) lo = mid + 1; else hi = mid; }
        int beg = lo;
        hi = N;
        while (lo < hi){ int mid = (lo + hi) >> 1; if (batch[mid] < g + 1) lo = mid + 1; else hi = mid; }
        cl[t] = (float)(lo - beg);
    }
    __syncthreads();
    for (int i = t; i < 8192; i += 1024)
        P[i] = pooled[i] / fmaxf(cl[i >> 6], 1.f);
    __syncthreads();
    for (int i = t; i < 8192; i += 1024){
        int br = i >> 12, r = (i >> 6) & 63, c = i & 63;
        const float* M1w = br ? M1wt : M1wb;
        const float* M1b = br ? M1bt : M1bb;
        float acc = M1b[c];
        int pb = (br << 12) + (r << 6);
        #pragma unroll 8
        for (int k = 0; k < 64; ++k) acc += P[pb + k] * M1w[(k << 6) + c];
        H[i] = fmaxf(acc, 0.f);
    }
    __syncthreads();
    for (int i = t; i < 8192; i += 1024){
        int br = i >> 12, r = (i >> 6) & 63, c = i & 63;
        const float* M2w = br ? M2wt : M2wb;
        const float* M2b = br ? M2bt : M2bb;
        float acc = M2b[c];
        int hb = (br << 12) + (r << 6);
        #pragma unroll 8
        for (int k = 0; k < 64; ++k) acc += H[hb + k] * M2w[(k << 6) + c];
        P[i] = acc;
    }
    __syncthreads();
    for (int i = t; i < 4096; i += 1024) H[i] = P[i] * P[4096 + i];
    __syncthreads();
    for (int i = t; i < 4096; i += 1024){
        int r = i >> 6, c = i & 63;
        float acc = Fb1[c];
        #pragma unroll 8
        for (int k = 0; k < 64; ++k) acc += H[(r << 6) + k] * Fw1[(k << 6) + c];
        P[i] = fmaxf(acc, 0.f);
    }
    __syncthreads();
    if (t < 128){
        int r = t >> 1, jc = t & 1;
        float acc = Fb2[jc];
        #pragma unroll 8
        for (int k = 0; k < 64; ++k) acc += P[(r << 6) + k] * Fw2[k * 2 + jc];
        out[t] = tanhf(acc);
    }
}

extern "C" void kernel_launch(void* const* d_in, const int* in_sizes, int n_in,
                              void* d_out, int out_size, void* d_ws, size_t ws_size,
                              hipStream_t stream){
    const int N = in_sizes[0] / 2;
    const int E = in_sizes[1] / 2;
    const int NB = (N + 511) >> BSH;   // nodes-per-bucket = 512, NB <= 128

    char* ws = (char*)d_ws;
    size_t off = 0;
    auto alloc = [&](size_t bytes) -> char* {
        char* p = ws + off;
        off += (bytes + 255) & ~(size_t)255;
        return p;
    };
    unsigned short* XL2h = (unsigned short*)alloc((size_t)2 * N * 64 * 2);  // EPAIR aliases this
    float* ES1 = (float*)alloc((size_t)2 * N * 2 * 4);
    float* ED1 = (float*)alloc((size_t)2 * N * 2 * 4);
    float* ES2 = (float*)alloc((size_t)2 * N * 4);
    float* ED2 = (float*)alloc((size_t)2 * N * 4);
    int* RS  = (int*)alloc((size_t)2 * (N + 1) * 4);
    int* CSR = (int*)alloc((size_t)2 * E * 4);
    int* BCUR = (int*)alloc((size_t)2 * NB * 4);
    float* POOLED = (float*)alloc(8192 * 4);
    unsigned short* W2T = (unsigned short*)alloc(2 * 8192 * 2);
    unsigned* EPAIR = (unsigned*)XL2h;   // 2*NB*ARENA*4 <= 2*N*128 bytes; dead after csr

    const float* xb   = (const float*)d_in[0];
    const int*   eib  = (const int*)  d_in[1];
    const int*   batchb = (const int*)d_in[2];
    const float* W1b  = (const float*)d_in[3];
    const float* a1sb = (const float*)d_in[4];
    const float* a1db = (const float*)d_in[5];
    const float* b1b  = (const float*)d_in[6];
    const float* W2b  = (const float*)d_in[7];
    const float* a2sb = (const float*)d_in[8];
    const float* a2db = (const float*)d_in[9];
    const float* b2b  = (const float*)d_in[10];
    const float* M1wb = (const float*)d_in[11];
    const float* M1bb = (const float*)d_in[12];
    const float* M2wb = (const float*)d_in[13];
    const float* M2bb = (const float*)d_in[14];
    const float* xt   = (const float*)d_in[15];
    const int*   eit  = (const int*)  d_in[16];
    const int*   batcht = (const int*)d_in[17];
    const float* W1t  = (const float*)d_in[18];
    const float* a1st = (const float*)d_in[19];
    const float* a1dt = (const float*)d_in[20];
    const float* b1t  = (const float*)d_in[21];
    const float* W2t  = (const float*)d_in[22];
    const float* a2st = (const float*)d_in[23];
    const float* a2dt = (const float*)d_in[24];
    const float* b2t  = (const float*)d_in[25];
    const float* M1wt = (const float*)d_in[26];
    const float* M1bt = (const float*)d_in[27];
    const float* M2wt = (const float*)d_in[28];
    const float* M2bt = (const float*)d_in[29];
    const float* Fw1  = (const float*)d_in[30];
    const float* Fb1  = (const float*)d_in[31];
    const float* Fw2  = (const float*)d_in[32];
    const float* Fb2  = (const float*)d_in[33];

    const int nodeBlocks = (N + 3) / 4;
    const int histBlocks = (E + CHUNK - 1) / CHUNK;
    const int tilesPer   = (N + 31) / 32;

    hipMemsetAsync(BCUR, 0, (size_t)2 * NB * 4, stream);
    preb_kernel<<<2 * histBlocks + 2 * nodeBlocks + 3, 256, 0, stream>>>(
        xb, xt, W1b, W1t, a1sb, a1st, a1db, a1dt, eib, eit, W2b, W2t,
        ES1, ED1, BCUR, EPAIR, W2T, POOLED, N, E, NB, nodeBlocks, histBlocks);
    csr_kernel<<<2 * NB, 256, 0, stream>>>(BCUR, EPAIR, RS, CSR, N, E, NB);
    a1f2_kernel<<<2 * tilesPer, 256, 0, stream>>>(
        xb, xt, ES1, ED1, CSR, RS, W1b, W1t, b1b, b1t, W2T,
        a2sb, a2st, a2db, a2dt, XL2h, ES2, ED2, N, E);
    a2pl_kernel<<<2 * nodeBlocks, 256, 0, stream>>>(
        XL2h, ES2, ED2, CSR, RS, b2b, b2t, batchb, batcht, POOLED, N, E);
    tail_kernel<<<1, 1024, 0, stream>>>(POOLED, batchb, batcht,
        M1wb, M1bb, M2wb, M2bb, M1wt, M1bt, M2wt, M2bt,
        Fw1, Fb1, Fw2, Fb2, (float*)d_out, N);
}

// Round 12
// 218.246 us; speedup vs baseline: 1.2809x; 1.0318x over previous
//
#include <hip/hip_runtime.h>
#include <math.h>

// ---------------------------------------------------------------------------
// DeepONet/GAT, fused pipeline (R12):
//   memset: BCUR (tiny)
//   preb  : feat1 logits only (es1/ed1, pre-scaled log2e) + W2->bf16^T
//           + POOLED zero + bin (edge bucket-sort into fixed arenas)
//   csr   : per-bucket CSR build (compact, window-local scatter)
//   a1f2  : LOW-RANK GAT1 agg, 8 lanes/node -> h1 = W1^T·sacc -> MFMA -> xl2
//   a2pl  : GAT2 agg, edge-list hoisted to lanes (readlane broadcast, deep
//           independent row-gathers) -> per-graph pools
//   tail  : counts + branch MLPs + combine + final head
// Buckets: 512 nodes (BSH=9), NB <= 128 (N <= 65536), arena 12288 edges.
// ---------------------------------------------------------------------------

#define BSH 9
#define CHUNK 4096
#define ARENA 12288
#define LOG2E 1.44269504088896f

using short8v = __attribute__((ext_vector_type(8))) short;
using f32x4  = __attribute__((ext_vector_type(4))) float;

__device__ __forceinline__ float leaky02(float x){ return fmaxf(x, 0.2f * x); }
__device__ __forceinline__ float elu1(float x){ return x > 0.f ? x : expm1f(x); }
__device__ __forceinline__ unsigned f2bf(float a){
    unsigned u = __float_as_uint(a);
    return (u + 0x7FFFu + ((u >> 16) & 1u)) >> 16;
}
__device__ __forceinline__ unsigned packbf(float a, float b){ return f2bf(a) | (f2bf(b) << 16); }
__device__ __forceinline__ float bflo(unsigned p){ return __uint_as_float(p << 16); }
__device__ __forceinline__ float bfhi(unsigned p){ return __uint_as_float(p & 0xFFFF0000u); }
__device__ __forceinline__ float bfs(unsigned short s){ return __uint_as_float(((unsigned)s) << 16); }

__device__ __forceinline__ int wave_incl_scan(int v, int lane){
    #pragma unroll
    for (int d = 1; d < 64; d <<= 1){ int u = __shfl_up(v, (unsigned)d, 64); if (lane >= d) v += u; }
    return v;
}

// feat1 logits + W2 transpose + POOLED zero + edge binning, grid-split.
__global__ __launch_bounds__(256) void preb_kernel(
    const float* __restrict__ xb, const float* __restrict__ xt,
    const float* __restrict__ W1b, const float* __restrict__ W1t,
    const float* __restrict__ a1sb, const float* __restrict__ a1st,
    const float* __restrict__ a1db, const float* __restrict__ a1dt,
    const int* __restrict__ eib, const int* __restrict__ eit,
    const float* __restrict__ W2b, const float* __restrict__ W2t,
    float* __restrict__ es1, float* __restrict__ ed1,
    int* __restrict__ bcur, unsigned* __restrict__ epair,
    unsigned short* __restrict__ w2T, float* __restrict__ pooled,
    int N, int E, int NB, int nodeBlocks, int histBlocks){
    int bid = blockIdx.x;
    int tid = threadIdx.x;
    __shared__ int hist[128], gpos[128];
    __shared__ int slots[CHUNK];
    if (bid < 2 * histBlocks){
        // ---- bin: bucket-sort one 4096-edge chunk into fixed arenas ----
        int br = (bid >= histBlocks) ? 1 : 0;
        int cb = bid - br * histBlocks;
        const int* ei = br ? eit : eib;
        int start = cb * CHUNK;
        int cnt = min(CHUNK, E - start);
        for (int i = tid; i < 128; i += 256) hist[i] = 0;
        __syncthreads();
        const int* dstp = ei + E + start;
        const int* srcp = ei + start;
        for (int li = tid; li < cnt; li += 256){
            int b = dstp[li] >> BSH;
            slots[li] = atomicAdd(&hist[b], 1);
        }
        __syncthreads();
        if (tid < NB){
            int h0 = hist[tid];
            gpos[tid] = (h0 > 0) ? atomicAdd(&bcur[br * NB + tid], h0) : 0;
        }
        __syncthreads();
        unsigned* ep = epair + (size_t)br * NB * ARENA;
        for (int li = tid; li < cnt; li += 256){
            int d = dstp[li];
            int b = d >> BSH;
            ep[(size_t)b * ARENA + gpos[b] + slots[li]] =
                ((unsigned)srcp[li] << BSH) | (unsigned)(d & ((1 << BSH) - 1));
        }
        return;
    }
    bid -= 2 * histBlocks;
    if (bid >= 2 * nodeBlocks){
        int xb2 = bid - 2 * nodeBlocks;
        if (xb2 < 2){
            // W2T[c][k] = bf16(W2[k][c]), per branch
            const float* W2 = xb2 ? W2t : W2b;
            for (int i = tid; i < 8192; i += 256){
                int c = i >> 7, k = i & 127;
                w2T[xb2 * 8192 + i] = (unsigned short)f2bf(W2[k * 64 + c]);
            }
        } else {
            for (int i = tid; i < 8192; i += 256) pooled[i] = 0.f;
        }
        return;
    }
    // ---- feat1 logits ----
    int br = (bid >= nodeBlocks) ? 1 : 0;
    int nb = bid - br * nodeBlocks;
    int n = (nb << 2) + (tid >> 6);
    int lane = tid & 63;
    if (n >= N) return;
    const float* x   = br ? xt   : xb;
    const float* W1  = br ? W1t  : W1b;
    const float* a1s = br ? a1st : a1sb;
    const float* a1d = br ? a1dt : a1db;
    float2 xv = ((const float2*)x)[n];
    float2 w0 = ((const float2*)W1)[lane];
    float2 w1 = ((const float2*)(W1 + 128))[lane];
    float xla = xv.x * w0.x + xv.y * w1.x;
    float xlb = xv.x * w0.y + xv.y * w1.y;
    float2 as = ((const float2*)a1s)[lane];
    float2 ad = ((const float2*)a1d)[lane];
    float ps = xla * as.x + xlb * as.y;
    float pd = xla * ad.x + xlb * ad.y;
    #pragma unroll
    for (int m = 16; m >= 1; m >>= 1){ ps += __shfl_xor(ps, m, 64); pd += __shfl_xor(pd, m, 64); }
    if ((lane & 31) == 0){
        int h = lane >> 5;
        es1[(size_t)br * N * 2 + n * 2 + h] = LOG2E * ps;
        ed1[(size_t)br * N * 2 + n * 2 + h] = LOG2E * pd;
    }
}

// per-bucket CSR: compact bases from bcur scan, local degrees, scatter src.
__global__ __launch_bounds__(256) void csr_kernel(
    const int* __restrict__ bcur, const unsigned* __restrict__ epair,
    int* __restrict__ rs, int* __restrict__ csr, int N, int E, int NB){
    int bid = blockIdx.x;
    int br = (bid >= NB) ? 1 : 0;
    int b = bid - br * NB;
    __shared__ int base2[128];
    __shared__ int deg[512], st[512];
    int tid = threadIdx.x, lane = tid & 63, wid = tid >> 6;
    if (wid == 0){
        int b0 = (lane < NB) ? bcur[br * NB + lane] : 0;
        int b1 = (64 + lane < NB) ? bcur[br * NB + 64 + lane] : 0;
        int g0 = wave_incl_scan(b0, lane); int gt = __shfl(g0, 63, 64);
        int g1 = wave_incl_scan(b1, lane);
        base2[lane] = g0 - b0; base2[64 + lane] = gt + g1 - b1;
    }
    for (int i = tid; i < 512; i += 256) deg[i] = 0;
    __syncthreads();
    int ebase = base2[b];
    int ecnt = bcur[br * NB + b];
    int n0 = b << BSH;
    int nodes = min(512, N - n0);
    const unsigned* ep = epair + ((size_t)br * NB + b) * ARENA;
    for (int i = tid; i < ecnt; i += 256) atomicAdd(&deg[ep[i] & 511u], 1);
    __syncthreads();
    if (wid == 0){
        int carry = 0;
        #pragma unroll
        for (int c = 0; c < 8; ++c){
            int v = deg[c * 64 + lane];
            int s = wave_incl_scan(v, lane);
            st[c * 64 + lane] = carry + s - v;
            carry += __shfl(s, 63, 64);
        }
    }
    __syncthreads();
    int* rsb = rs + (size_t)br * (N + 1);
    for (int i = tid; i < nodes; i += 256) rsb[n0 + i] = ebase + st[i];
    if (b == NB - 1 && tid == 0) rsb[N] = ebase + ecnt;
    for (int i = tid; i < 512; i += 256) deg[i] = st[i];
    __syncthreads();
    int* csrb = csr + (size_t)br * E + ebase;
    for (int i = tid; i < ecnt; i += 256){
        unsigned p = ep[i];
        int pos = atomicAdd(&deg[p & 511u], 1);
        csrb[pos] = (int)(p >> BSH);
    }
}

// Low-rank GAT1 aggregation (8 lanes/node) + h1 reconstruction + MFMA + logits2.
// Block = 32 nodes, 4 waves; wave = 8 nodes, 8 lanes each.
__global__ __launch_bounds__(256) void a1f2_kernel(
    const float* __restrict__ xB, const float* __restrict__ xT,
    const float* __restrict__ es1, const float* __restrict__ ed1,
    const int* __restrict__ csr, const int* __restrict__ rs,
    const float* __restrict__ W1b, const float* __restrict__ W1t,
    const float* __restrict__ b1b, const float* __restrict__ b1t,
    const unsigned short* __restrict__ w2T,
    const float* __restrict__ a2sb, const float* __restrict__ a2st,
    const float* __restrict__ a2db, const float* __restrict__ a2dt,
    unsigned short* __restrict__ xl2h, float* __restrict__ es2, float* __restrict__ ed2,
    int N, int E){
    int bid = blockIdx.x;
    int br = bid & 1;                 // branch parity == XCD parity class
    int n0 = (bid >> 1) << 5;         // 32 nodes per block
    const float* x  = br ? xT : xB;
    const float* es = es1 + (size_t)br * N * 2;
    const float* ed = ed1 + (size_t)br * N * 2;
    const int* cs = csr + (size_t)br * E;
    const int* rsb = rs + (size_t)br * (N + 1);
    const float* W1 = br ? W1t : W1b;
    const float* b1 = br ? b1t : b1b;
    const float* a2s = br ? a2st : a2sb;
    const float* a2d = br ? a2dt : a2db;

    __shared__ float sacc[32][6];     // per node: d0, s0x, s0y, d1, s1x, s1y
    __shared__ unsigned hl[32][68];   // h1 tile, packed bf16 pairs, padded
    __shared__ float psa[4][32], pda[4][32];
    int tid = threadIdx.x, lane = tid & 63, w = tid >> 6;
    int g = lane >> 3, sl = lane & 7;
    int row = w * 8 + g;
    int n = n0 + row;
    bool valid = n < N;

    // ---- aggregation: 8 lanes per node, register accumulators ----
    float2 edv = ((const float2*)ed)[valid ? n : 0];
    int beg = 0, end = 0;
    if (valid){ beg = rsb[n]; end = rsb[n + 1]; }
    float d0 = 0.f, s0x = 0.f, s0y = 0.f, d1 = 0.f, s1x = 0.f, s1y = 0.f;
    if (valid && sl == 0){            // self-loop term
        float2 xv = ((const float2*)x)[n];
        float2 ev = ((const float2*)es)[n];
        float w0 = exp2f(leaky02(ev.x + edv.x));
        float w1 = exp2f(leaky02(ev.y + edv.y));
        d0 = w0; s0x = w0 * xv.x; s0y = w0 * xv.y;
        d1 = w1; s1x = w1 * xv.x; s1y = w1 * xv.y;
    }
    for (int j = beg + sl; j < end; j += 8){
        int s = cs[j];
        float2 xv = ((const float2*)x)[s];
        float2 ev = ((const float2*)es)[s];
        float w0 = exp2f(leaky02(ev.x + edv.x));
        float w1 = exp2f(leaky02(ev.y + edv.y));
        d0 += w0; s0x += w0 * xv.x; s0y += w0 * xv.y;
        d1 += w1; s1x += w1 * xv.x; s1y += w1 * xv.y;
    }
    #pragma unroll
    for (int m = 1; m < 8; m <<= 1){
        d0  += __shfl_xor(d0, m, 64);
        s0x += __shfl_xor(s0x, m, 64);
        s0y += __shfl_xor(s0y, m, 64);
        d1  += __shfl_xor(d1, m, 64);
        s1x += __shfl_xor(s1x, m, 64);
        s1y += __shfl_xor(s1y, m, 64);
    }
    if (sl == 0){
        sacc[row][0] = d0; sacc[row][1] = s0x; sacc[row][2] = s0y;
        sacc[row][3] = d1; sacc[row][4] = s1x; sacc[row][5] = s1y;
    }
    __syncthreads();

    // ---- reconstruct h1 = elu(W1^T sacc / denom + b1), 8 rows per wave ----
    int h = lane >> 5;
    float2 w0c = ((const float2*)W1)[lane];          // W1[0, 2l..2l+1]
    float2 w1c = ((const float2*)(W1 + 128))[lane];  // W1[1, 2l..2l+1]
    float b1lo = b1[lane * 2], b1hi = b1[lane * 2 + 1];
    #pragma unroll
    for (int nn = 0; nn < 8; ++nn){
        int r2 = w * 8 + nn;
        int nr = n0 + r2;
        float dinv = 1.f / sacc[r2][3 * h];
        float sx = sacc[r2][3 * h + 1], sy = sacc[r2][3 * h + 2];
        float va = (sx * w0c.x + sy * w1c.x) * dinv + b1lo;
        float vb = (sx * w0c.y + sy * w1c.y) * dinv + b1hi;
        hl[r2][lane] = (nr < N) ? packbf(elu1(va), elu1(vb)) : 0u;
    }

    int lr = lane & 15, lq = lane >> 4;
    // B fragments straight from global bf16 W2T (L1-resident 16KB/branch)
    const unsigned short* wtp = w2T + br * 8192 + (w * 16 + lr) * 128 + lq * 8;
    short8v bf0 = *(const short8v*)(wtp);
    short8v bf1 = *(const short8v*)(wtp + 32);
    short8v bf2 = *(const short8v*)(wtp + 64);
    short8v bf3 = *(const short8v*)(wtp + 96);
    float a2sv = a2s[w * 16 + lr];
    float a2dv = a2d[w * 16 + lr];
    __syncthreads();
    // ---- MFMA: 2 row-tiles x this wave's 16-col tile ----
    #pragma unroll
    for (int rt = 0; rt < 2; ++rt){
        int rb = rt << 4;
        f32x4 ac = {0.f, 0.f, 0.f, 0.f};
        ac = __builtin_amdgcn_mfma_f32_16x16x32_bf16(*(const short8v*)&hl[rb + lr][lq * 4], bf0, ac, 0, 0, 0);
        ac = __builtin_amdgcn_mfma_f32_16x16x32_bf16(*(const short8v*)&hl[rb + lr][16 + lq * 4], bf1, ac, 0, 0, 0);
        ac = __builtin_amdgcn_mfma_f32_16x16x32_bf16(*(const short8v*)&hl[rb + lr][32 + lq * 4], bf2, ac, 0, 0, 0);
        ac = __builtin_amdgcn_mfma_f32_16x16x32_bf16(*(const short8v*)&hl[rb + lr][48 + lq * 4], bf3, ac, 0, 0, 0);
        #pragma unroll
        for (int reg = 0; reg < 4; ++reg){
            int r = rb + lq * 4 + reg;
            int nr = n0 + r;
            float v = ac[reg];
            if (nr < N)
                xl2h[((size_t)br * N + nr) * 64 + w * 16 + lr] = (unsigned short)f2bf(v);
            float ps = v * a2sv, pd = v * a2dv;
            ps += __shfl_xor(ps, 1, 64); ps += __shfl_xor(ps, 2, 64);
            ps += __shfl_xor(ps, 4, 64); ps += __shfl_xor(ps, 8, 64);
            pd += __shfl_xor(pd, 1, 64); pd += __shfl_xor(pd, 2, 64);
            pd += __shfl_xor(pd, 4, 64); pd += __shfl_xor(pd, 8, 64);
            if (lr == 0){ psa[w][r] = ps; pda[w][r] = pd; }
        }
    }
    __syncthreads();
    if (tid < 32){
        int nr = n0 + tid;
        if (nr < N)
            es2[(size_t)br * N + nr] = LOG2E * (psa[0][tid] + psa[1][tid] + psa[2][tid] + psa[3][tid]);
    } else if (tid < 64){
        int r = tid - 32;
        int nr = n0 + r;
        if (nr < N)
            ed2[(size_t)br * N + nr] = LOG2E * (pda[0][r] + pda[1][r] + pda[2][r] + pda[3][r]);
    }
}

// Fused GAT2 aggregation + per-graph pooled sums.
// Edge list + weights hoisted to lanes (one coalesced cs load, per-lane
// es gather + exp2); denom via wave reduce; inner loop = readlane broadcast
// + independent 128B row gathers (weight-0 padding to a multiple of 8).
__global__ __launch_bounds__(256) void a2pl_kernel(
    const unsigned short* __restrict__ xl2h, const float* __restrict__ es2, const float* __restrict__ ed2,
    const int* __restrict__ csr, const int* __restrict__ rs,
    const float* __restrict__ b2b, const float* __restrict__ b2t,
    const int* __restrict__ batchb, const int* __restrict__ batcht,
    float* __restrict__ pooled, int N, int E){
    int bid = blockIdx.x;
    int br = bid & 1;                 // branch parity == XCD parity class
    int tid = threadIdx.x, lane = tid & 63, w = tid >> 6;
    int n = ((bid >> 1) << 2) + w;
    const unsigned short* xlt = xl2h + (size_t)br * N * 64;
    const float* es = es2 + (size_t)br * N;
    const float* ed = ed2 + (size_t)br * N;
    const int* cs = csr + (size_t)br * E;
    const int* rsb = rs + (size_t)br * (N + 1);
    const float* b2 = br ? b2t : b2b;
    const int* batch = br ? batcht : batchb;
    float hv = 0.f;
    int g = -1;
    if (n < N){
        float edn = ed[n];
        float wself = exp2f(leaky02(es[n] + edn));
        float denom = wself;
        float acc = wself * bfs(xlt[(unsigned)(n * 64) + lane]);
        int beg = rsb[n];
        int end = rsb[n + 1];
        for (int base = beg; base < end; base += 64){
            int cnt = min(64, end - base);
            int myidx = cs[base + min(lane, cnt - 1)];
            float wmine = (lane < cnt) ? exp2f(leaky02(es[myidx] + edn)) : 0.f;
            float ws = wmine;
            #pragma unroll
            for (int m = 1; m < 64; m <<= 1) ws += __shfl_xor(ws, m, 64);
            denom += ws;
            int cntR = (cnt + 7) & ~7;
            for (int q = 0; q < cntR; q += 8){
                #pragma unroll
                for (int qq = 0; qq < 8; ++qq){
                    int s = __builtin_amdgcn_readlane(myidx, q + qq);
                    float wq = __uint_as_float(
                        __builtin_amdgcn_readlane(__float_as_uint(wmine), q + qq));
                    float v = bfs(xlt[(unsigned)(s * 64) + lane]);
                    acc += wq * v;
                }
            }
        }
        hv = elu1(acc / denom + b2[lane]);
        g = batch[n];
    }
    __shared__ float red[4][64];
    __shared__ int gid[4];
    red[w][lane] = hv;
    if (lane == 0) gid[w] = g;
    __syncthreads();
    if (w == 0){
        int g0 = gid[0], g1 = gid[1], g2 = gid[2], g3 = gid[3];
        float* pb = pooled + (size_t)br * 4096;
        if (g0 >= 0 && g0 == g1 && g1 == g2 && g2 == g3){
            float s = (red[0][lane] + red[1][lane]) + (red[2][lane] + red[3][lane]);
            atomicAdd(&pb[g0 * 64 + lane], s);
        } else {
            #pragma unroll
            for (int q = 0; q < 4; ++q)
                if (gid[q] >= 0) atomicAdd(&pb[gid[q] * 64 + lane], red[q][lane]);
        }
    }
}

// counts (binary search on sorted batch) + branch MLPs + combine + final head
__global__ __launch_bounds__(1024) void tail_kernel(
    const float* __restrict__ pooled,
    const int* __restrict__ batchb, const int* __restrict__ batcht,
    const float* __restrict__ M1wb, const float* __restrict__ M1bb,
    const float* __restrict__ M2wb, const float* __restrict__ M2bb,
    const float* __restrict__ M1wt, const float* __restrict__ M1bt,
    const float* __restrict__ M2wt, const float* __restrict__ M2bt,
    const float* __restrict__ Fw1, const float* __restrict__ Fb1,
    const float* __restrict__ Fw2, const float* __restrict__ Fb2,
    float* __restrict__ out, int N){
    __shared__ float P[8192];
    __shared__ float H[8192];
    __shared__ float cl[128];
    int t = threadIdx.x;
    if (t < 128){
        int br = t >> 6, g = t & 63;
        const int* batch = br ? batcht : batchb;
        int lo = 0, hi = N;
        while (lo < hi){ int mid = (lo + hi) >> 1; if (batch[mid] < g) lo = mid + 1; else hi = mid; }
        int beg = lo;
        hi = N;
        while (lo < hi){ int mid = (lo + hi) >> 1; if (batch[mid] < g + 1) lo = mid + 1; else hi = mid; }
        cl[t] = (float)(lo - beg);
    }
    __syncthreads();
    for (int i = t; i < 8192; i += 1024)
        P[i] = pooled[i] / fmaxf(cl[i >> 6], 1.f);
    __syncthreads();
    for (int i = t; i < 8192; i += 1024){
        int br = i >> 12, r = (i >> 6) & 63, c = i & 63;
        const float* M1w = br ? M1wt : M1wb;
        const float* M1b = br ? M1bt : M1bb;
        float acc = M1b[c];
        int pb = (br << 12) + (r << 6);
        #pragma unroll 8
        for (int k = 0; k < 64; ++k) acc += P[pb + k] * M1w[(k << 6) + c];
        H[i] = fmaxf(acc, 0.f);
    }
    __syncthreads();
    for (int i = t; i < 8192; i += 1024){
        int br = i >> 12, r = (i >> 6) & 63, c = i & 63;
        const float* M2w = br ? M2wt : M2wb;
        const float* M2b = br ? M2bt : M2bb;
        float acc = M2b[c];
        int hb = (br << 12) + (r << 6);
        #pragma unroll 8
        for (int k = 0; k < 64; ++k) acc += H[hb + k] * M2w[(k << 6) + c];
        P[i] = acc;
    }
    __syncthreads();
    for (int i = t; i < 4096; i += 1024) H[i] = P[i] * P[4096 + i];
    __syncthreads();
    for (int i = t; i < 4096; i += 1024){
        int r = i >> 6, c = i & 63;
        float acc = Fb1[c];
        #pragma unroll 8
        for (int k = 0; k < 64; ++k) acc += H[(r << 6) + k] * Fw1[(k << 6) + c];
        P[i] = fmaxf(acc, 0.f);
    }
    __syncthreads();
    if (t < 128){
        int r = t >> 1, jc = t & 1;
        float acc = Fb2[jc];
        #pragma unroll 8
        for (int k = 0; k < 64; ++k) acc += P[(r << 6) + k] * Fw2[k * 2 + jc];
        out[t] = tanhf(acc);
    }
}

extern "C" void kernel_launch(void* const* d_in, const int* in_sizes, int n_in,
                              void* d_out, int out_size, void* d_ws, size_t ws_size,
                              hipStream_t stream){
    const int N = in_sizes[0] / 2;
    const int E = in_sizes[1] / 2;
    const int NB = (N + 511) >> BSH;   // nodes-per-bucket = 512, NB <= 128

    char* ws = (char*)d_ws;
    size_t off = 0;
    auto alloc = [&](size_t bytes) -> char* {
        char* p = ws + off;
        off += (bytes + 255) & ~(size_t)255;
        return p;
    };
    unsigned short* XL2h = (unsigned short*)alloc((size_t)2 * N * 64 * 2);  // EPAIR aliases this
    float* ES1 = (float*)alloc((size_t)2 * N * 2 * 4);
    float* ED1 = (float*)alloc((size_t)2 * N * 2 * 4);
    float* ES2 = (float*)alloc((size_t)2 * N * 4);
    float* ED2 = (float*)alloc((size_t)2 * N * 4);
    int* RS  = (int*)alloc((size_t)2 * (N + 1) * 4);
    int* CSR = (int*)alloc((size_t)2 * E * 4);
    int* BCUR = (int*)alloc((size_t)2 * NB * 4);
    float* POOLED = (float*)alloc(8192 * 4);
    unsigned short* W2T = (unsigned short*)alloc(2 * 8192 * 2);
    unsigned* EPAIR = (unsigned*)XL2h;   // 2*NB*ARENA*4 <= 2*N*128 bytes; dead after csr

    const float* xb   = (const float*)d_in[0];
    const int*   eib  = (const int*)  d_in[1];
    const int*   batchb = (const int*)d_in[2];
    const float* W1b  = (const float*)d_in[3];
    const float* a1sb = (const float*)d_in[4];
    const float* a1db = (const float*)d_in[5];
    const float* b1b  = (const float*)d_in[6];
    const float* W2b  = (const float*)d_in[7];
    const float* a2sb = (const float*)d_in[8];
    const float* a2db = (const float*)d_in[9];
    const float* b2b  = (const float*)d_in[10];
    const float* M1wb = (const float*)d_in[11];
    const float* M1bb = (const float*)d_in[12];
    const float* M2wb = (const float*)d_in[13];
    const float* M2bb = (const float*)d_in[14];
    const float* xt   = (const float*)d_in[15];
    const int*   eit  = (const int*)  d_in[16];
    const int*   batcht = (const int*)d_in[17];
    const float* W1t  = (const float*)d_in[18];
    const float* a1st = (const float*)d_in[19];
    const float* a1dt = (const float*)d_in[20];
    const float* b1t  = (const float*)d_in[21];
    const float* W2t  = (const float*)d_in[22];
    const float* a2st = (const float*)d_in[23];
    const float* a2dt = (const float*)d_in[24];
    const float* b2t  = (const float*)d_in[25];
    const float* M1wt = (const float*)d_in[26];
    const float* M1bt = (const float*)d_in[27];
    const float* M2wt = (const float*)d_in[28];
    const float* M2bt = (const float*)d_in[29];
    const float* Fw1  = (const float*)d_in[30];
    const float* Fb1  = (const float*)d_in[31];
    const float* Fw2  = (const float*)d_in[32];
    const float* Fb2  = (const float*)d_in[33];

    const int nodeBlocks = (N + 3) / 4;
    const int histBlocks = (E + CHUNK - 1) / CHUNK;
    const int tilesPer   = (N + 31) / 32;

    hipMemsetAsync(BCUR, 0, (size_t)2 * NB * 4, stream);
    preb_kernel<<<2 * histBlocks + 2 * nodeBlocks + 3, 256, 0, stream>>>(
        xb, xt, W1b, W1t, a1sb, a1st, a1db, a1dt, eib, eit, W2b, W2t,
        ES1, ED1, BCUR, EPAIR, W2T, POOLED, N, E, NB, nodeBlocks, histBlocks);
    csr_kernel<<<2 * NB, 256, 0, stream>>>(BCUR, EPAIR, RS, CSR, N, E, NB);
    a1f2_kernel<<<2 * tilesPer, 256, 0, stream>>>(
        xb, xt, ES1, ED1, CSR, RS, W1b, W1t, b1b, b1t, W2T,
        a2sb, a2st, a2db, a2dt, XL2h, ES2, ED2, N, E);
    a2pl_kernel<<<2 * nodeBlocks, 256, 0, stream>>>(
        XL2h, ES2, ED2, CSR, RS, b2b, b2t, batchb, batcht, POOLED, N, E);
    tail_kernel<<<1, 1024, 0, stream>>>(POOLED, batchb, batcht,
        M1wb, M1bb, M2wb, M2bb, M1wt, M1bt, M2wt, M2bt,
        Fw1, Fb1, Fw2, Fb2, (float*)d_out, N);
}

// Round 13
// 202.353 us; speedup vs baseline: 1.3815x; 1.0785x over previous
//
#include <hip/hip_runtime.h>
#include <math.h>

// ---------------------------------------------------------------------------
// DeepONet/GAT, fused pipeline (R13):
//   memset: BCUR (tiny)
//   preb  : W2->bf16^T + rank-2 logit coeffs (alpha = LOG2E * W1^T a) +
//           POOLED zero + bin (edge bucket-sort into fixed arenas)
//   csr   : per-bucket CSR build (compact, window-local scatter)
//   a1f2  : LOW-RANK GAT1 agg (logits on-the-fly from x[src], 8 lanes/node)
//           -> h1 = W1^T·sacc -> MFMA -> xl2 + layer-2 logits
//   a2pl  : GAT2 agg, 16-deep independent row-gather batches -> pools
//   tail  : counts + branch MLPs + combine + final head
// Buckets: 512 nodes (BSH=9), NB <= 128 (N <= 65536), arena 12288 edges.
// ---------------------------------------------------------------------------

#define BSH 9
#define CHUNK 4096
#define ARENA 12288
#define LOG2E 1.44269504088896f

using short8v = __attribute__((ext_vector_type(8))) short;
using f32x4  = __attribute__((ext_vector_type(4))) float;

__device__ __forceinline__ float leaky02(float x){ return fmaxf(x, 0.2f * x); }
__device__ __forceinline__ float elu1(float x){ return x > 0.f ? x : expm1f(x); }
__device__ __forceinline__ unsigned f2bf(float a){
    unsigned u = __float_as_uint(a);
    return (u + 0x7FFFu + ((u >> 16) & 1u)) >> 16;
}
__device__ __forceinline__ unsigned packbf(float a, float b){ return f2bf(a) | (f2bf(b) << 16); }
__device__ __forceinline__ float bflo(unsigned p){ return __uint_as_float(p << 16); }
__device__ __forceinline__ float bfhi(unsigned p){ return __uint_as_float(p & 0xFFFF0000u); }
__device__ __forceinline__ float bfs(unsigned short s){ return __uint_as_float(((unsigned)s) << 16); }

__device__ __forceinline__ int wave_incl_scan(int v, int lane){
    #pragma unroll
    for (int d = 1; d < 64; d <<= 1){ int u = __shfl_up(v, (unsigned)d, 64); if (lane >= d) v += u; }
    return v;
}

// W2 transpose + alpha coeffs + POOLED zero + edge binning, grid-split.
__global__ __launch_bounds__(256) void preb_kernel(
    const float* __restrict__ W1b, const float* __restrict__ W1t,
    const float* __restrict__ a1sb, const float* __restrict__ a1st,
    const float* __restrict__ a1db, const float* __restrict__ a1dt,
    const int* __restrict__ eib, const int* __restrict__ eit,
    const float* __restrict__ W2b, const float* __restrict__ W2t,
    int* __restrict__ bcur, unsigned* __restrict__ epair,
    unsigned short* __restrict__ w2T, float* __restrict__ alph,
    float* __restrict__ pooled,
    int N, int E, int NB, int histBlocks){
    int bid = blockIdx.x;
    int tid = threadIdx.x;
    __shared__ int hist[128], gpos[128];
    __shared__ int slots[CHUNK];
    if (bid < 2 * histBlocks){
        // ---- bin: bucket-sort one 4096-edge chunk into fixed arenas ----
        int br = (bid >= histBlocks) ? 1 : 0;
        int cb = bid - br * histBlocks;
        const int* ei = br ? eit : eib;
        int start = cb * CHUNK;
        int cnt = min(CHUNK, E - start);
        for (int i = tid; i < 128; i += 256) hist[i] = 0;
        __syncthreads();
        const int* dstp = ei + E + start;
        const int* srcp = ei + start;
        for (int li = tid; li < cnt; li += 256){
            int b = dstp[li] >> BSH;
            slots[li] = atomicAdd(&hist[b], 1);
        }
        __syncthreads();
        if (tid < NB){
            int h0 = hist[tid];
            gpos[tid] = (h0 > 0) ? atomicAdd(&bcur[br * NB + tid], h0) : 0;
        }
        __syncthreads();
        unsigned* ep = epair + (size_t)br * NB * ARENA;
        for (int li = tid; li < cnt; li += 256){
            int d = dstp[li];
            int b = d >> BSH;
            ep[(size_t)b * ARENA + gpos[b] + slots[li]] =
                ((unsigned)srcp[li] << BSH) | (unsigned)(d & ((1 << BSH) - 1));
        }
        return;
    }
    bid -= 2 * histBlocks;
    if (bid < 2){
        // W2T[c][k] = bf16(W2[k][c]) + alpha coeffs, per branch
        int br = bid;
        const float* W2 = br ? W2t : W2b;
        for (int i = tid; i < 8192; i += 256){
            int c = i >> 7, k = i & 127;
            w2T[br * 8192 + i] = (unsigned short)f2bf(W2[k * 64 + c]);
        }
        if (tid < 64){
            const float* W1  = br ? W1t  : W1b;
            const float* a1s = br ? a1st : a1sb;
            const float* a1d = br ? a1dt : a1db;
            int lane = tid;
            for (int k = 0; k < 8; ++k){
                int sd = k >> 2, h = (k >> 1) & 1, xr = k & 1;
                const float* av = sd ? a1d : a1s;
                float p = W1[xr * 128 + h * 64 + lane] * av[h * 64 + lane];
                #pragma unroll
                for (int m = 32; m >= 1; m >>= 1) p += __shfl_xor(p, m, 64);
                if (lane == 0) alph[br * 8 + k] = LOG2E * p;
            }
        }
    } else {
        for (int i = tid; i < 8192; i += 256) pooled[i] = 0.f;
    }
}

// per-bucket CSR: compact bases from bcur scan, local degrees, scatter src.
__global__ __launch_bounds__(256) void csr_kernel(
    const int* __restrict__ bcur, const unsigned* __restrict__ epair,
    int* __restrict__ rs, int* __restrict__ csr, int N, int E, int NB){
    int bid = blockIdx.x;
    int br = (bid >= NB) ? 1 : 0;
    int b = bid - br * NB;
    __shared__ int base2[128];
    __shared__ int deg[512], st[512];
    int tid = threadIdx.x, lane = tid & 63, wid = tid >> 6;
    if (wid == 0){
        int b0 = (lane < NB) ? bcur[br * NB + lane] : 0;
        int b1 = (64 + lane < NB) ? bcur[br * NB + 64 + lane] : 0;
        int g0 = wave_incl_scan(b0, lane); int gt = __shfl(g0, 63, 64);
        int g1 = wave_incl_scan(b1, lane);
        base2[lane] = g0 - b0; base2[64 + lane] = gt + g1 - b1;
    }
    for (int i = tid; i < 512; i += 256) deg[i] = 0;
    __syncthreads();
    int ebase = base2[b];
    int ecnt = bcur[br * NB + b];
    int n0 = b << BSH;
    int nodes = min(512, N - n0);
    const unsigned* ep = epair + ((size_t)br * NB + b) * ARENA;
    for (int i = tid; i < ecnt; i += 256) atomicAdd(&deg[ep[i] & 511u], 1);
    __syncthreads();
    if (wid == 0){
        int carry = 0;
        #pragma unroll
        for (int c = 0; c < 8; ++c){
            int v = deg[c * 64 + lane];
            int s = wave_incl_scan(v, lane);
            st[c * 64 + lane] = carry + s - v;
            carry += __shfl(s, 63, 64);
        }
    }
    __syncthreads();
    int* rsb = rs + (size_t)br * (N + 1);
    for (int i = tid; i < nodes; i += 256) rsb[n0 + i] = ebase + st[i];
    if (b == NB - 1 && tid == 0) rsb[N] = ebase + ecnt;
    for (int i = tid; i < 512; i += 256) deg[i] = st[i];
    __syncthreads();
    int* csrb = csr + (size_t)br * E + ebase;
    for (int i = tid; i < ecnt; i += 256){
        unsigned p = ep[i];
        int pos = atomicAdd(&deg[p & 511u], 1);
        csrb[pos] = (int)(p >> BSH);
    }
}

// Low-rank GAT1 aggregation (8 lanes/node, logits on-the-fly) + h1
// reconstruction + MFMA + layer-2 logits. Block = 32 nodes, 4 waves.
__global__ __launch_bounds__(256) void a1f2_kernel(
    const float* __restrict__ xB, const float* __restrict__ xT,
    const float* __restrict__ alph,
    const int* __restrict__ csr, const int* __restrict__ rs,
    const float* __restrict__ W1b, const float* __restrict__ W1t,
    const float* __restrict__ b1b, const float* __restrict__ b1t,
    const unsigned short* __restrict__ w2T,
    const float* __restrict__ a2sb, const float* __restrict__ a2st,
    const float* __restrict__ a2db, const float* __restrict__ a2dt,
    unsigned short* __restrict__ xl2h, float* __restrict__ es2, float* __restrict__ ed2,
    int N, int E){
    int bid = blockIdx.x;
    int br = bid & 1;                 // branch parity == XCD parity class
    int n0 = (bid >> 1) << 5;         // 32 nodes per block
    const float* x  = br ? xT : xB;
    const int* cs = csr + (size_t)br * E;
    const int* rsb = rs + (size_t)br * (N + 1);
    const float* W1 = br ? W1t : W1b;
    const float* b1 = br ? b1t : b1b;
    const float* a2s = br ? a2st : a2sb;
    const float* a2d = br ? a2dt : a2db;
    const float* al = alph + br * 8;
    float as0x = al[0], as0y = al[1], as1x = al[2], as1y = al[3];
    float ad0x = al[4], ad0y = al[5], ad1x = al[6], ad1y = al[7];

    __shared__ float sacc[32][6];     // per node: d0, s0x, s0y, d1, s1x, s1y
    __shared__ unsigned hl[32][68];   // h1 tile, packed bf16 pairs, padded
    __shared__ float psa[4][32], pda[4][32];
    int tid = threadIdx.x, lane = tid & 63, w = tid >> 6;
    int g = lane >> 3, sl = lane & 7;
    int row = w * 8 + g;
    int n = n0 + row;
    bool valid = n < N;

    // ---- aggregation: 8 lanes per node, register accumulators ----
    float2 xn = ((const float2*)x)[valid ? n : 0];
    float edv0 = ad0x * xn.x + ad0y * xn.y;      // dst logits (pre-scaled)
    float edv1 = ad1x * xn.x + ad1y * xn.y;
    int beg = 0, end = 0;
    if (valid){ beg = rsb[n]; end = rsb[n + 1]; }
    float d0 = 0.f, s0x = 0.f, s0y = 0.f, d1 = 0.f, s1x = 0.f, s1y = 0.f;
    if (valid && sl == 0){            // self-loop term
        float e0 = as0x * xn.x + as0y * xn.y;
        float e1 = as1x * xn.x + as1y * xn.y;
        float w0 = exp2f(leaky02(e0 + edv0));
        float w1 = exp2f(leaky02(e1 + edv1));
        d0 = w0; s0x = w0 * xn.x; s0y = w0 * xn.y;
        d1 = w1; s1x = w1 * xn.x; s1y = w1 * xn.y;
    }
    for (int j = beg + sl; j < end; j += 8){
        int s = cs[j];
        float2 xv = ((const float2*)x)[s];
        float e0 = as0x * xv.x + as0y * xv.y;
        float e1 = as1x * xv.x + as1y * xv.y;
        float w0 = exp2f(leaky02(e0 + edv0));
        float w1 = exp2f(leaky02(e1 + edv1));
        d0 += w0; s0x += w0 * xv.x; s0y += w0 * xv.y;
        d1 += w1; s1x += w1 * xv.x; s1y += w1 * xv.y;
    }
    #pragma unroll
    for (int m = 1; m < 8; m <<= 1){
        d0  += __shfl_xor(d0, m, 64);
        s0x += __shfl_xor(s0x, m, 64);
        s0y += __shfl_xor(s0y, m, 64);
        d1  += __shfl_xor(d1, m, 64);
        s1x += __shfl_xor(s1x, m, 64);
        s1y += __shfl_xor(s1y, m, 64);
    }
    if (sl == 0){
        sacc[row][0] = d0; sacc[row][1] = s0x; sacc[row][2] = s0y;
        sacc[row][3] = d1; sacc[row][4] = s1x; sacc[row][5] = s1y;
    }
    __syncthreads();

    // ---- reconstruct h1 = elu(W1^T sacc / denom + b1), 8 rows per wave ----
    int h = lane >> 5;
    float2 w0c = ((const float2*)W1)[lane];          // W1[0, 2l..2l+1]
    float2 w1c = ((const float2*)(W1 + 128))[lane];  // W1[1, 2l..2l+1]
    float b1lo = b1[lane * 2], b1hi = b1[lane * 2 + 1];
    #pragma unroll
    for (int nn = 0; nn < 8; ++nn){
        int r2 = w * 8 + nn;
        int nr = n0 + r2;
        float dinv = 1.f / sacc[r2][3 * h];
        float sx = sacc[r2][3 * h + 1], sy = sacc[r2][3 * h + 2];
        float va = (sx * w0c.x + sy * w1c.x) * dinv + b1lo;
        float vb = (sx * w0c.y + sy * w1c.y) * dinv + b1hi;
        hl[r2][lane] = (nr < N) ? packbf(elu1(va), elu1(vb)) : 0u;
    }

    int lr = lane & 15, lq = lane >> 4;
    // B fragments straight from global bf16 W2T (L1-resident 16KB/branch)
    const unsigned short* wtp = w2T + br * 8192 + (w * 16 + lr) * 128 + lq * 8;
    short8v bf0 = *(const short8v*)(wtp);
    short8v bf1 = *(const short8v*)(wtp + 32);
    short8v bf2 = *(const short8v*)(wtp + 64);
    short8v bf3 = *(const short8v*)(wtp + 96);
    float a2sv = a2s[w * 16 + lr];
    float a2dv = a2d[w * 16 + lr];
    __syncthreads();
    // ---- MFMA: 2 row-tiles x this wave's 16-col tile ----
    #pragma unroll
    for (int rt = 0; rt < 2; ++rt){
        int rb = rt << 4;
        f32x4 ac = {0.f, 0.f, 0.f, 0.f};
        ac = __builtin_amdgcn_mfma_f32_16x16x32_bf16(*(const short8v*)&hl[rb + lr][lq * 4], bf0, ac, 0, 0, 0);
        ac = __builtin_amdgcn_mfma_f32_16x16x32_bf16(*(const short8v*)&hl[rb + lr][16 + lq * 4], bf1, ac, 0, 0, 0);
        ac = __builtin_amdgcn_mfma_f32_16x16x32_bf16(*(const short8v*)&hl[rb + lr][32 + lq * 4], bf2, ac, 0, 0, 0);
        ac = __builtin_amdgcn_mfma_f32_16x16x32_bf16(*(const short8v*)&hl[rb + lr][48 + lq * 4], bf3, ac, 0, 0, 0);
        #pragma unroll
        for (int reg = 0; reg < 4; ++reg){
            int r = rb + lq * 4 + reg;
            int nr = n0 + r;
            float v = ac[reg];
            if (nr < N)
                xl2h[((size_t)br * N + nr) * 64 + w * 16 + lr] = (unsigned short)f2bf(v);
            float ps = v * a2sv, pd = v * a2dv;
            ps += __shfl_xor(ps, 1, 64); ps += __shfl_xor(ps, 2, 64);
            ps += __shfl_xor(ps, 4, 64); ps += __shfl_xor(ps, 8, 64);
            pd += __shfl_xor(pd, 1, 64); pd += __shfl_xor(pd, 2, 64);
            pd += __shfl_xor(pd, 4, 64); pd += __shfl_xor(pd, 8, 64);
            if (lr == 0){ psa[w][r] = ps; pda[w][r] = pd; }
        }
    }
    __syncthreads();
    if (tid < 32){
        int nr = n0 + tid;
        if (nr < N)
            es2[(size_t)br * N + nr] = LOG2E * (psa[0][tid] + psa[1][tid] + psa[2][tid] + psa[3][tid]);
    } else if (tid < 64){
        int r = tid - 32;
        int nr = n0 + r;
        if (nr < N)
            ed2[(size_t)br * N + nr] = LOG2E * (pda[0][r] + pda[1][r] + pda[2][r] + pda[3][r]);
    }
}

// Fused GAT2 aggregation + per-graph pooled sums.
// Edge list + weights hoisted to lanes; 16-deep independent row-gather
// batches (weight-0 padding); denom via wave reduce.
__global__ __launch_bounds__(256) void a2pl_kernel(
    const unsigned short* __restrict__ xl2h, const float* __restrict__ es2, const float* __restrict__ ed2,
    const int* __restrict__ csr, const int* __restrict__ rs,
    const float* __restrict__ b2b, const float* __restrict__ b2t,
    const int* __restrict__ batchb, const int* __restrict__ batcht,
    float* __restrict__ pooled, int N, int E){
    int bid = blockIdx.x;
    int br = bid & 1;                 // branch parity == XCD parity class
    int tid = threadIdx.x, lane = tid & 63, w = tid >> 6;
    int n = ((bid >> 1) << 2) + w;
    const unsigned short* xlt = xl2h + (size_t)br * N * 64;
    const float* es = es2 + (size_t)br * N;
    const float* ed = ed2 + (size_t)br * N;
    const int* cs = csr + (size_t)br * E;
    const int* rsb = rs + (size_t)br * (N + 1);
    const float* b2 = br ? b2t : b2b;
    const int* batch = br ? batcht : batchb;
    float hv = 0.f;
    int g = -1;
    if (n < N){
        g = batch[n];
        float edn = ed[n];
        float wself = exp2f(leaky02(es[n] + edn));
        float denom = wself;
        float acc = wself * bfs(xlt[(unsigned)(n * 64) + lane]);
        int beg = rsb[n];
        int end = rsb[n + 1];
        for (int base = beg; base < end; base += 64){
            int cnt = min(64, end - base);
            int myidx = cs[base + min(lane, cnt - 1)];
            float wmine = (lane < cnt) ? exp2f(leaky02(es[myidx] + edn)) : 0.f;
            float ws = wmine;
            #pragma unroll
            for (int m = 1; m < 64; m <<= 1) ws += __shfl_xor(ws, m, 64);
            denom += ws;
            int cntR = (cnt + 15) & ~15;
            for (int q0 = 0; q0 < cntR; q0 += 16){
                float vv[16];
                #pragma unroll
                for (int qq = 0; qq < 16; ++qq){
                    int s = __builtin_amdgcn_readlane(myidx, q0 + qq);
                    vv[qq] = bfs(xlt[(unsigned)(s * 64) + lane]);
                }
                #pragma unroll
                for (int qq = 0; qq < 16; ++qq){
                    float wq = __uint_as_float(
                        __builtin_amdgcn_readlane(__float_as_uint(wmine), q0 + qq));
                    acc += wq * vv[qq];
                }
            }
        }
        hv = elu1(acc / denom + b2[lane]);
    }
    __shared__ float red[4][64];
    __shared__ int gid[4];
    red[w][lane] = hv;
    if (lane == 0) gid[w] = g;
    __syncthreads();
    if (w == 0){
        int g0 = gid[0], g1 = gid[1], g2 = gid[2], g3 = gid[3];
        float* pb = pooled + (size_t)br * 4096;
        if (g0 >= 0 && g0 == g1 && g1 == g2 && g2 == g3){
            float s = (red[0][lane] + red[1][lane]) + (red[2][lane] + red[3][lane]);
            atomicAdd(&pb[g0 * 64 + lane], s);
        } else {
            #pragma unroll
            for (int q = 0; q < 4; ++q)
                if (gid[q] >= 0) atomicAdd(&pb[gid[q] * 64 + lane], red[q][lane]);
        }
    }
}

// counts (binary search on sorted batch) + branch MLPs + combine + final head
__global__ __launch_bounds__(1024) void tail_kernel(
    const float* __restrict__ pooled,
    const int* __restrict__ batchb, const int* __restrict__ batcht,
    const float* __restrict__ M1wb, const float* __restrict__ M1bb,
    const float* __restrict__ M2wb, const float* __restrict__ M2bb,
    const float* __restrict__ M1wt, const float* __restrict__ M1bt,
    const float* __restrict__ M2wt, const float* __restrict__ M2bt,
    const float* __restrict__ Fw1, const float* __restrict__ Fb1,
    const float* __restrict__ Fw2, const float* __restrict__ Fb2,
    float* __restrict__ out, int N){
    __shared__ float P[8192];
    __shared__ float H[8192];
    __shared__ float cl[128];
    int t = threadIdx.x;
    if (t < 128){
        int br = t >> 6, g = t & 63;
        const int* batch = br ? batcht : batchb;
        int lo = 0, hi = N;
        while (lo < hi){ int mid = (lo + hi) >> 1; if (batch[mid] < g) lo = mid + 1; else hi = mid; }
        int beg = lo;
        hi = N;
        while (lo < hi){ int mid = (lo + hi) >> 1; if (batch[mid] < g + 1) lo = mid + 1; else hi = mid; }
        cl[t] = (float)(lo - beg);
    }
    __syncthreads();
    for (int i = t; i < 8192; i += 1024)
        P[i] = pooled[i] / fmaxf(cl[i >> 6], 1.f);
    __syncthreads();
    for (int i = t; i < 8192; i += 1024){
        int br = i >> 12, r = (i >> 6) & 63, c = i & 63;
        const float* M1w = br ? M1wt : M1wb;
        const float* M1b = br ? M1bt : M1bb;
        float acc = M1b[c];
        int pb = (br << 12) + (r << 6);
        #pragma unroll 8
        for (int k = 0; k < 64; ++k) acc += P[pb + k] * M1w[(k << 6) + c];
        H[i] = fmaxf(acc, 0.f);
    }
    __syncthreads();
    for (int i = t; i < 8192; i += 1024){
        int br = i >> 12, r = (i >> 6) & 63, c = i & 63;
        const float* M2w = br ? M2wt : M2wb;
        const float* M2b = br ? M2bt : M2bb;
        float acc = M2b[c];
        int hb = (br << 12) + (r << 6);
        #pragma unroll 8
        for (int k = 0; k < 64; ++k) acc += H[hb + k] * M2w[(k << 6) + c];
        P[i] = acc;
    }
    __syncthreads();
    for (int i = t; i < 4096; i += 1024) H[i] = P[i] * P[4096 + i];
    __syncthreads();
    for (int i = t; i < 4096; i += 1024){
        int r = i >> 6, c = i & 63;
        float acc = Fb1[c];
        #pragma unroll 8
        for (int k = 0; k < 64; ++k) acc += H[(r << 6) + k] * Fw1[(k << 6) + c];
        P[i] = fmaxf(acc, 0.f);
    }
    __syncthreads();
    if (t < 128){
        int r = t >> 1, jc = t & 1;
        float acc = Fb2[jc];
        #pragma unroll 8
        for (int k = 0; k < 64; ++k) acc += P[(r << 6) + k] * Fw2[k * 2 + jc];
        out[t] = tanhf(acc);
    }
}

extern "C" void kernel_launch(void* const* d_in, const int* in_sizes, int n_in,
                              void* d_out, int out_size, void* d_ws, size_t ws_size,
                              hipStream_t stream){
    const int N = in_sizes[0] / 2;
    const int E = in_sizes[1] / 2;
    const int NB = (N + 511) >> BSH;   // nodes-per-bucket = 512, NB <= 128

    char* ws = (char*)d_ws;
    size_t off = 0;
    auto alloc = [&](size_t bytes) -> char* {
        char* p = ws + off;
        off += (bytes + 255) & ~(size_t)255;
        return p;
    };
    unsigned short* XL2h = (unsigned short*)alloc((size_t)2 * N * 64 * 2);  // EPAIR aliases this
    float* ES2 = (float*)alloc((size_t)2 * N * 4);
    float* ED2 = (float*)alloc((size_t)2 * N * 4);
    int* RS  = (int*)alloc((size_t)2 * (N + 1) * 4);
    int* CSR = (int*)alloc((size_t)2 * E * 4);
    int* BCUR = (int*)alloc((size_t)2 * NB * 4);
    float* POOLED = (float*)alloc(8192 * 4);
    unsigned short* W2T = (unsigned short*)alloc(2 * 8192 * 2);
    float* ALPH = (float*)alloc(16 * 4);
    unsigned* EPAIR = (unsigned*)XL2h;   // 2*NB*ARENA*4 <= 2*N*128 bytes; dead after csr

    const float* xb   = (const float*)d_in[0];
    const int*   eib  = (const int*)  d_in[1];
    const int*   batchb = (const int*)d_in[2];
    const float* W1b  = (const float*)d_in[3];
    const float* a1sb = (const float*)d_in[4];
    const float* a1db = (const float*)d_in[5];
    const float* b1b  = (const float*)d_in[6];
    const float* W2b  = (const float*)d_in[7];
    const float* a2sb = (const float*)d_in[8];
    const float* a2db = (const float*)d_in[9];
    const float* b2b  = (const float*)d_in[10];
    const float* M1wb = (const float*)d_in[11];
    const float* M1bb = (const float*)d_in[12];
    const float* M2wb = (const float*)d_in[13];
    const float* M2bb = (const float*)d_in[14];
    const float* xt   = (const float*)d_in[15];
    const int*   eit  = (const int*)  d_in[16];
    const int*   batcht = (const int*)d_in[17];
    const float* W1t  = (const float*)d_in[18];
    const float* a1st = (const float*)d_in[19];
    const float* a1dt = (const float*)d_in[20];
    const float* b1t  = (const float*)d_in[21];
    const float* W2t  = (const float*)d_in[22];
    const float* a2st = (const float*)d_in[23];
    const float* a2dt = (const float*)d_in[24];
    const float* b2t  = (const float*)d_in[25];
    const float* M1wt = (const float*)d_in[26];
    const float* M1bt = (const float*)d_in[27];
    const float* M2wt = (const float*)d_in[28];
    const float* M2bt = (const float*)d_in[29];
    const float* Fw1  = (const float*)d_in[30];
    const float* Fb1  = (const float*)d_in[31];
    const float* Fw2  = (const float*)d_in[32];
    const float* Fb2  = (const float*)d_in[33];

    const int nodeBlocks = (N + 3) / 4;
    const int histBlocks = (E + CHUNK - 1) / CHUNK;
    const int tilesPer   = (N + 31) / 32;

    hipMemsetAsync(BCUR, 0, (size_t)2 * NB * 4, stream);
    preb_kernel<<<2 * histBlocks + 3, 256, 0, stream>>>(
        W1b, W1t, a1sb, a1st, a1db, a1dt, eib, eit, W2b, W2t,
        BCUR, EPAIR, W2T, ALPH, POOLED, N, E, NB, histBlocks);
    csr_kernel<<<2 * NB, 256, 0, stream>>>(BCUR, EPAIR, RS, CSR, N, E, NB);
    a1f2_kernel<<<2 * tilesPer, 256, 0, stream>>>(
        xb, xt, ALPH, CSR, RS, W1b, W1t, b1b, b1t, W2T,
        a2sb, a2st, a2db, a2dt, XL2h, ES2, ED2, N, E);
    a2pl_kernel<<<2 * nodeBlocks, 256, 0, stream>>>(
        XL2h, ES2, ED2, CSR, RS, b2b, b2t, batchb, batcht, POOLED, N, E);
    tail_kernel<<<1, 1024, 0, stream>>>(POOLED, batchb, batcht,
        M1wb, M1bb, M2wb, M2bb, M1wt, M1bt, M2wt, M2bt,
        Fw1, Fb1, Fw2, Fb2, (float*)d_out, N);
}